// Round 1
// baseline (451.075 us; speedup 1.0000x reference)
//
#include <hip/hip_runtime.h>
#include <hip/hip_bf16.h>

// Problem constants (fixed by setup_inputs)
#define BATCH 2
#define NPTS  8192
#define KS    16
#define KNN   8

// Kernel geometry
#define QB    64            // queries per block
#define NWAVE 8             // waves per block (512 threads)
#define TILE  1024          // candidates staged per LDS tile
#define CPW   (TILE/NWAVE)  // candidates per wave per tile = 128
#define NBLK  (BATCH * NPTS / QB)  // 256 blocks

__global__ void zero_out_kernel(float* out) { out[0] = 0.0f; }

__global__ __launch_bounds__(512) void knn_loss_kernel(
    const float* __restrict__ pc,    // (B, N, 3)
    const float* __restrict__ mask,  // (B, N, KS)
    float* __restrict__ out)         // scalar
{
    __shared__ float4 tile[TILE];              // 16 KB: candidate x,y,z,|c|^2
    __shared__ float  sd[NWAVE * QB * KNN];    // 16 KB: partial top-8 d2
    __shared__ int    si[NWAVE * QB * KNN];    // 16 KB: partial top-8 idx
    __shared__ int    fidx[QB * KNN];          //  2 KB: final idx after radius test
    __shared__ float  red[NWAVE];

    const int t = threadIdx.x;
    const int q = t & (QB - 1);   // query slot within block
    const int s = t >> 6;         // wave id (QB == wave size == 64)
    const int blk = blockIdx.x;
    const int b  = blk / (NPTS / QB);
    const int q0 = (blk % (NPTS / QB)) * QB;
    const int qi = q0 + q;        // query index within batch

    const float* pcb = pc + (size_t)b * NPTS * 3;

    // Query point + norm (same fma sequence as staging -> self d2 == 0 exactly)
    const float qx = pcb[qi * 3 + 0];
    const float qy = pcb[qi * 3 + 1];
    const float qz = pcb[qi * 3 + 2];
    const float qs = fmaf(qz, qz, fmaf(qy, qy, qx * qx));

    float d[KNN];
    int   id[KNN];
#pragma unroll
    for (int k = 0; k < KNN; ++k) { d[k] = 1e30f; id[k] = 0; }

    for (int tb = 0; tb < NPTS; tb += TILE) {
        // Stage TILE candidates (512 threads -> 2 points each)
        for (int p = t; p < TILE; p += NWAVE * 64) {
            const int ci = tb + p;
            const float x = pcb[ci * 3 + 0];
            const float y = pcb[ci * 3 + 1];
            const float z = pcb[ci * 3 + 2];
            const float sq = fmaf(z, z, fmaf(y, y, x * x));
            tile[p] = make_float4(x, y, z, sq);
        }
        __syncthreads();

        const int j0 = s * CPW;  // wave-uniform subrange -> broadcast LDS reads
#pragma unroll 4
        for (int j = 0; j < CPW; ++j) {
            const float4 c = tile[j0 + j];
            float dot = fmaf(c.z, qz, fmaf(c.y, qy, c.x * qx));
            float d2  = fmaf(-2.0f, dot, qs + c.w);
            d2 = fmaxf(d2, 0.0f);
            if (d2 < d[KNN - 1]) {           // rarely taken after warm-up
                float cd = d2;
                int   ci2 = tb + j0 + j;
#pragma unroll
                for (int k = 0; k < KNN; ++k) {
                    if (cd < d[k]) {
                        float td = d[k]; d[k] = cd; cd = td;
                        int   ti = id[k]; id[k] = ci2; ci2 = ti;
                    }
                }
            }
        }
        __syncthreads();
    }

    // Publish partial lists
#pragma unroll
    for (int k = 0; k < KNN; ++k) {
        sd[(s * QB + q) * KNN + k] = d[k];
        si[(s * QB + q) * KNN + k] = id[k];
    }
    __syncthreads();

    // Wave 0: merge the 8 partial lists per query, apply radius test
    if (s == 0) {
        float md[KNN]; int mi[KNN];
#pragma unroll
        for (int k = 0; k < KNN; ++k) { md[k] = d[k]; mi[k] = id[k]; }
        for (int l = 1; l < NWAVE; ++l) {
#pragma unroll
            for (int k = 0; k < KNN; ++k) {
                float cd = sd[(l * QB + q) * KNN + k];
                int   ci2 = si[(l * QB + q) * KNN + k];
#pragma unroll
                for (int m = 0; m < KNN; ++m) {
                    if (cd < md[m]) {
                        float td = md[m]; md[m] = cd; cd = td;
                        int   ti = mi[m]; mi[m] = ci2; ci2 = ti;
                    }
                }
            }
        }
        const int id0 = mi[0];  // self (d2 == 0)
#pragma unroll
        for (int k = 0; k < KNN; ++k) {
            // reference: idx = where(sqrt(d2) > 0.1, self_idx, idx)
            const bool keep = !(sqrtf(md[k]) > 0.1f);
            fidx[q * KNN + k] = keep ? mi[k] : id0;
        }
    }
    __syncthreads();

    // Loss gather: 512 threads <-> 64 queries x 8 neighbors
    const int q2 = t >> 3;
    const int j  = t & 7;
    const int qg = q0 + q2;
    const int nb = fidx[q2 * KNN + j];
    const float* mrow = mask + ((size_t)b * NPTS + qg) * KS;
    const float* nrow = mask + ((size_t)b * NPTS + nb) * KS;
    float acc = 0.0f;
#pragma unroll
    for (int c = 0; c < KS; c += 4) {
        const float4 a = *(const float4*)(mrow + c);
        const float4 v = *(const float4*)(nrow + c);
        acc += fabsf(a.x - v.x) + fabsf(a.y - v.y) +
               fabsf(a.z - v.z) + fabsf(a.w - v.w);
    }

    // Block reduction: wave shuffle -> LDS -> single atomic per block
#pragma unroll
    for (int off = 32; off > 0; off >>= 1) acc += __shfl_down(acc, off);
    if ((t & 63) == 0) red[s] = acc;
    __syncthreads();
    if (t == 0) {
        float sum = 0.0f;
#pragma unroll
        for (int i = 0; i < NWAVE; ++i) sum += red[i];
        atomicAdd(out, sum * (1.0f / (BATCH * NPTS * KNN)));
    }
}

extern "C" void kernel_launch(void* const* d_in, const int* in_sizes, int n_in,
                              void* d_out, int out_size, void* d_ws, size_t ws_size,
                              hipStream_t stream) {
    const float* pc   = (const float*)d_in[0];  // (2, 8192, 3)
    const float* mask = (const float*)d_in[1];  // (2, 8192, 16)
    float* out = (float*)d_out;                 // scalar, poisoned 0xAA each call

    hipLaunchKernelGGL(zero_out_kernel, dim3(1), dim3(1), 0, stream, out);
    hipLaunchKernelGGL(knn_loss_kernel, dim3(NBLK), dim3(512), 0, stream,
                       pc, mask, out);
}

// Round 2
// 212.114 us; speedup vs baseline: 2.1266x; 2.1266x over previous
//
#include <hip/hip_runtime.h>
#include <hip/hip_bf16.h>

// Problem constants (fixed by setup_inputs)
#define BATCH 2
#define NPTS  8192
#define KS    16
#define KNN   8
#define R2LOOSE 0.0101f   // loose prefilter; exact sqrt(d2)>0.1 test applied at end

// Kernel geometry
#define QB    64            // queries per block (= wave size)
#define NWAVE 8             // waves per block (512 threads)
#define TILE  1024          // candidates staged per LDS tile
#define CPW   (TILE/NWAVE)  // candidates per wave per tile = 128
#define NBLK  (BATCH * NPTS / QB)  // 256 blocks

__global__ void zero_out_kernel(float* out) { out[0] = 0.0f; }

__global__ __launch_bounds__(512) void knn_loss_kernel(
    const float* __restrict__ pc,    // (B, N, 3)
    const float* __restrict__ mask,  // (B, N, KS)
    float* __restrict__ out)         // scalar
{
    __shared__ float4 tile[TILE];              // 16 KB: candidate x,y,z,0.5*|c|^2
    __shared__ float  sd[NWAVE * QB * KNN];    // 16 KB: partial top-8 d2
    __shared__ int    si[NWAVE * QB * KNN];    // 16 KB: partial top-8 idx
    __shared__ int    fidx[QB * KNN];          //  2 KB: final idx after radius test
    __shared__ float  red[NWAVE];

    const int t = threadIdx.x;
    const int q = t & (QB - 1);   // query slot within block
    const int s = t >> 6;         // wave id
    const int blk = blockIdx.x;
    const int b  = blk / (NPTS / QB);
    const int q0 = (blk % (NPTS / QB)) * QB;
    const int qi = q0 + q;        // query index within batch

    const float* pcb = pc + (size_t)b * NPTS * 3;

    const float qx = pcb[qi * 3 + 0];
    const float qy = pcb[qi * 3 + 1];
    const float qz = pcb[qi * 3 + 2];
    const float qs = fmaf(qz, qz, fmaf(qy, qy, qx * qx));

    // top-8 list: init to the radius ball; slots that never fill fail the
    // exact radius test at the end -> replaced by self -> contribute 0.
    float d[KNN];
    int   id[KNN];
#pragma unroll
    for (int k = 0; k < KNN; ++k) { d[k] = R2LOOSE; id[k] = qi; }

    // guard: candidate passes iff d2 <= d[7]  <=>  t >= (qs - d[7])*0.5
    float negthr = (qs - R2LOOSE) * 0.5f;

    for (int tb = 0; tb < NPTS; tb += TILE) {
        // Stage TILE candidates (512 threads -> 2 points each)
        for (int p = t; p < TILE; p += NWAVE * 64) {
            const int ci = tb + p;
            const float x = pcb[ci * 3 + 0];
            const float y = pcb[ci * 3 + 1];
            const float z = pcb[ci * 3 + 2];
            const float sq = fmaf(z, z, fmaf(y, y, x * x));
            tile[p] = make_float4(x, y, z, 0.5f * sq);
        }
        __syncthreads();

        const int j0 = s * CPW;  // wave-uniform subrange -> broadcast LDS reads
        for (int j = 0; j < CPW; j += 8) {
            float4 c[8];
#pragma unroll
            for (int u = 0; u < 8; ++u) c[u] = tile[j0 + j + u];
#pragma unroll
            for (int u = 0; u < 8; ++u) {
                // tt = dot(c,q) - 0.5*|c|^2 ;  d2 = qs - 2*tt
                const float tt = fmaf(c[u].x, qx,
                                 fmaf(c[u].y, qy,
                                 fmaf(c[u].z, qz, -c[u].w)));
                if (tt >= negthr) {            // d2 <= current 8th-best (rare)
                    float cd = fmaxf(fmaf(-2.0f, tt, qs), 0.0f);
                    int   ci2 = tb + j0 + j + u;
                    if (cd < d[KNN - 1]) {
#pragma unroll
                        for (int k = 0; k < KNN; ++k) {
                            if (cd < d[k]) {
                                float td = d[k]; d[k] = cd; cd = td;
                                int   ti = id[k]; id[k] = ci2; ci2 = ti;
                            }
                        }
                        negthr = (qs - d[KNN - 1]) * 0.5f;
                    }
                }
            }
        }
        __syncthreads();
    }

    // Publish partial lists
#pragma unroll
    for (int k = 0; k < KNN; ++k) {
        sd[(s * QB + q) * KNN + k] = d[k];
        si[(s * QB + q) * KNN + k] = id[k];
    }
    __syncthreads();

    // Wave 0: merge the 8 partial lists per query, apply exact radius test
    if (s == 0) {
        float md[KNN]; int mi[KNN];
#pragma unroll
        for (int k = 0; k < KNN; ++k) { md[k] = d[k]; mi[k] = id[k]; }
        for (int l = 1; l < NWAVE; ++l) {
#pragma unroll
            for (int k = 0; k < KNN; ++k) {
                float cd = sd[(l * QB + q) * KNN + k];
                int   ci2 = si[(l * QB + q) * KNN + k];
                if (cd < md[KNN - 1]) {        // skip sentinels fast
#pragma unroll
                    for (int m = 0; m < KNN; ++m) {
                        if (cd < md[m]) {
                            float td = md[m]; md[m] = cd; cd = td;
                            int   ti = mi[m]; mi[m] = ci2; ci2 = ti;
                        }
                    }
                }
            }
        }
        const int id0 = mi[0];  // self (d2 ~ 0)
#pragma unroll
        for (int k = 0; k < KNN; ++k) {
            // reference: idx = where(sqrt(d2) > 0.1, self_idx, idx)
            const bool keep = !(sqrtf(md[k]) > 0.1f);
            fidx[q * KNN + k] = keep ? mi[k] : id0;
        }
    }
    __syncthreads();

    // Loss gather: 512 threads <-> 64 queries x 8 neighbors
    const int q2 = t >> 3;
    const int j  = t & 7;
    const int qg = q0 + q2;
    const int nb = fidx[q2 * KNN + j];
    const float* mrow = mask + ((size_t)b * NPTS + qg) * KS;
    const float* nrow = mask + ((size_t)b * NPTS + nb) * KS;
    float acc = 0.0f;
#pragma unroll
    for (int c = 0; c < KS; c += 4) {
        const float4 a = *(const float4*)(mrow + c);
        const float4 v = *(const float4*)(nrow + c);
        acc += fabsf(a.x - v.x) + fabsf(a.y - v.y) +
               fabsf(a.z - v.z) + fabsf(a.w - v.w);
    }

    // Block reduction: wave shuffle -> LDS -> single atomic per block
#pragma unroll
    for (int off = 32; off > 0; off >>= 1) acc += __shfl_down(acc, off);
    if ((t & 63) == 0) red[s] = acc;
    __syncthreads();
    if (t == 0) {
        float sum = 0.0f;
#pragma unroll
        for (int i = 0; i < NWAVE; ++i) sum += red[i];
        atomicAdd(out, sum * (1.0f / (BATCH * NPTS * KNN)));
    }
}

extern "C" void kernel_launch(void* const* d_in, const int* in_sizes, int n_in,
                              void* d_out, int out_size, void* d_ws, size_t ws_size,
                              hipStream_t stream) {
    const float* pc   = (const float*)d_in[0];  // (2, 8192, 3)
    const float* mask = (const float*)d_in[1];  // (2, 8192, 16)
    float* out = (float*)d_out;                 // scalar, poisoned 0xAA each call

    hipLaunchKernelGGL(zero_out_kernel, dim3(1), dim3(1), 0, stream, out);
    hipLaunchKernelGGL(knn_loss_kernel, dim3(NBLK), dim3(512), 0, stream,
                       pc, mask, out);
}

// Round 3
// 126.126 us; speedup vs baseline: 3.5764x; 1.6818x over previous
//
#include <hip/hip_runtime.h>
#include <hip/hip_bf16.h>

// Problem constants (fixed by setup_inputs)
#define BATCH 2
#define NPTS  8192
#define KS    16
#define KNN   8
#define R2LOOSE 0.0101f   // loose prefilter; exact radius test applied at end

// Kernel geometry
#define QB    64              // queries per block (= wave size; lane <-> query)
#define NWAVE 16              // waves per block (1024 threads)
#define CPW   (NPTS / NWAVE)  // candidates per wave = 512
#define NBLK  (BATCH * NPTS / QB)  // 256 blocks
#define KEYMASK 0xFFFFE000u   // high 19 bits of d2; low 13 bits hold idx

// Pass 1: pack candidates as (x, y, z, -0.5*|c|^2) and zero the output scalar.
__global__ void pack_kernel(const float* __restrict__ pc,
                            float4* __restrict__ cand,
                            float* __restrict__ out) {
    const int i = blockIdx.x * 256 + threadIdx.x;
    if (i == 0) out[0] = 0.0f;
    if (i < BATCH * NPTS) {
        const float x = pc[3 * i + 0];
        const float y = pc[3 * i + 1];
        const float z = pc[3 * i + 2];
        const float sq = fmaf(z, z, fmaf(y, y, x * x));
        cand[i] = make_float4(x, y, z, -0.5f * sq);
    }
}

__global__ __launch_bounds__(1024) void knn_loss_kernel(
    const float*  __restrict__ pc,    // (B, N, 3)
    const float*  __restrict__ mask,  // (B, N, KS)
    const float4* __restrict__ cand,  // (B*N) packed (x,y,z,-0.5|c|^2)
    float* __restrict__ out)          // scalar
{
    __shared__ unsigned skeys[NWAVE * QB * KNN];  // 32 KB partial top-8 keys
    __shared__ int      fidx[QB * KNN];           //  2 KB final neighbor idx
    __shared__ float    red[NWAVE];

    const int t = threadIdx.x;
    const int q = t & (QB - 1);   // query slot (lane)
    const int s = t >> 6;         // wave id 0..15
    const int blk = blockIdx.x;
    const int b  = blk >> 7;              // blk / (NPTS/QB=128)
    const int q0 = (blk & 127) * QB;
    const int qi = q0 + q;                // query index within batch

    const float*  pcb = pc   + (size_t)b * NPTS * 3;
    const float4* cb  = cand + (size_t)b * NPTS;

    const float qx = pcb[qi * 3 + 0];
    const float qy = pcb[qi * 3 + 1];
    const float qz = pcb[qi * 3 + 2];
    const float qs = fmaf(qz, qz, fmaf(qy, qy, qx * qx));

    // Sorted top-8 as packed keys: (d2 bits & KEYMASK) | candidate idx.
    // Sentinel decodes to ~R2LOOSE; unfilled slots -> self -> contribute 0.
    const unsigned SENT = (__float_as_uint(R2LOOSE) & KEYMASK) | 0x1FFFu;
    unsigned keys[KNN];
#pragma unroll
    for (int k = 0; k < KNN; ++k) keys[k] = SENT;

    // candidate passes iff d2 <= thr  <=>  tt >= (qs - thr)*0.5
    float negthr = (qs - __uint_as_float(SENT & KEYMASK)) * 0.5f;

    // Wave-uniform candidate window -> scalar (s_load) candidate fetches.
    const int w0 = __builtin_amdgcn_readfirstlane(s) * CPW;

#pragma unroll 32
    for (int j = 0; j < CPW; ++j) {
        const float4 c = cb[w0 + j];   // uniform address: SGPR broadcast
        // tt = dot(c,q) - 0.5*|c|^2 ;  d2 = qs - 2*tt
        const float tt = fmaf(c.x, qx, fmaf(c.y, qy, fmaf(c.z, qz, c.w)));
        if (tt >= negthr) {            // wave-rare
            const float d2 = fmaxf(fmaf(-2.0f, tt, qs), 0.0f);
            unsigned key = (__float_as_uint(d2) & KEYMASK) | (unsigned)(w0 + j);
            // branchless sorted insert (compare-exchange cascade)
#pragma unroll
            for (int k = 0; k < KNN; ++k) {
                const unsigned mn = min(key, keys[k]);
                const unsigned mx = max(key, keys[k]);
                keys[k] = mn; key = mx;
            }
            negthr = (qs - __uint_as_float(keys[KNN - 1] & KEYMASK)) * 0.5f;
        }
    }

    // Publish partial lists
#pragma unroll
    for (int k = 0; k < KNN; ++k) skeys[(s * QB + q) * KNN + k] = keys[k];
    __syncthreads();

    // Wave 0: merge 16 partial lists per query, exact radius test, emit fidx
    if (s == 0) {
        unsigned md[KNN];
#pragma unroll
        for (int k = 0; k < KNN; ++k) md[k] = keys[k];
        for (int l = 1; l < NWAVE; ++l) {
#pragma unroll
            for (int k = 0; k < KNN; ++k) {
                unsigned ky = skeys[(l * QB + q) * KNN + k];
                if (ky < md[KNN - 1]) {   // skip sentinels fast
#pragma unroll
                    for (int m = 0; m < KNN; ++m) {
                        const unsigned mn = min(ky, md[m]);
                        const unsigned mx = max(ky, md[m]);
                        md[m] = mn; ky = mx;
                    }
                }
            }
        }
#pragma unroll
        for (int k = 0; k < KNN; ++k) {
            const unsigned ky = md[k];
            int nb;
            if (ky == SENT) {
                nb = qi;  // unfilled -> self (contributes 0, matches ref)
            } else {
                const int ci = (int)(ky & 0x1FFFu);
                // exact d2 in difference form (no truncation bias)
                const float dx = pcb[3 * ci + 0] - qx;
                const float dy = pcb[3 * ci + 1] - qy;
                const float dz = pcb[3 * ci + 2] - qz;
                const float d2 = fmaf(dx, dx, fmaf(dy, dy, dz * dz));
                // reference: idx = where(sqrt(d2) > 0.1, self_idx, idx)
                nb = (sqrtf(d2) > 0.1f) ? qi : ci;
            }
            fidx[q * KNN + k] = nb;
        }
    }
    __syncthreads();

    // Loss gather: 1024 threads <-> 64 queries x 8 neighbors x 2 half-rows
    const int q2 = t >> 4;
    const int j2 = (t >> 1) & 7;
    const int h  = t & 1;
    const int qg = q0 + q2;
    const int nb = fidx[q2 * KNN + j2];
    const float* mrow = mask + ((size_t)b * NPTS + qg) * KS + h * 8;
    const float* nrow = mask + ((size_t)b * NPTS + nb) * KS + h * 8;
    float acc = 0.0f;
#pragma unroll
    for (int c = 0; c < 8; c += 4) {
        const float4 a = *(const float4*)(mrow + c);
        const float4 v = *(const float4*)(nrow + c);
        acc += fabsf(a.x - v.x) + fabsf(a.y - v.y) +
               fabsf(a.z - v.z) + fabsf(a.w - v.w);
    }

    // Block reduction: wave shuffle -> LDS -> one atomic per block
#pragma unroll
    for (int off = 32; off > 0; off >>= 1) acc += __shfl_down(acc, off);
    if ((t & 63) == 0) red[s] = acc;
    __syncthreads();
    if (t == 0) {
        float sum = 0.0f;
#pragma unroll
        for (int i = 0; i < NWAVE; ++i) sum += red[i];
        atomicAdd(out, sum * (1.0f / (BATCH * NPTS * KNN)));
    }
}

extern "C" void kernel_launch(void* const* d_in, const int* in_sizes, int n_in,
                              void* d_out, int out_size, void* d_ws, size_t ws_size,
                              hipStream_t stream) {
    const float* pc   = (const float*)d_in[0];  // (2, 8192, 3)
    const float* mask = (const float*)d_in[1];  // (2, 8192, 16)
    float* out   = (float*)d_out;               // scalar, poisoned 0xAA each call
    float4* cand = (float4*)d_ws;               // 16384 * 16 B = 256 KB scratch

    hipLaunchKernelGGL(pack_kernel, dim3((BATCH * NPTS + 255) / 256), dim3(256),
                       0, stream, pc, cand, out);
    hipLaunchKernelGGL(knn_loss_kernel, dim3(NBLK), dim3(1024), 0, stream,
                       pc, mask, cand, out);
}

// Round 4
// 103.190 us; speedup vs baseline: 4.3713x; 1.2223x over previous
//
#include <hip/hip_runtime.h>
#include <hip/hip_bf16.h>

// Problem constants (fixed by setup_inputs)
#define BATCH 2
#define NPTS  8192
#define KS    16
#define KNN   8
#define R2LOOSE 0.0101f   // loose prefilter ball; exact radius test at end
#define KEYMASK 0xFFFFE000u  // high 19 bits of d2; low 13 bits hold idx

// Kernel geometry
#define QB       64                // queries per block (= wave size)
#define NWAVE    16                // waves per block (1024 threads)
#define NTHREADS (QB * NWAVE)      // 1024
#define CPW      (NPTS / NWAVE)    // candidates per wave = 512
#define GS       4                 // candidates per load group (64 B)
#define NG       (CPW / GS)        // 128 groups per wave
#define CAP      16                // collect capacity per (lane, window)
#define NBLK     (BATCH * NPTS / QB)  // 256 blocks

// Pass 1: pack candidates as (x, y, z, -0.5*|c|^2); zero the output scalar.
__global__ void pack_kernel(const float* __restrict__ pc,
                            float4* __restrict__ cand,
                            float* __restrict__ out) {
    const int i = blockIdx.x * 256 + threadIdx.x;
    if (i == 0) out[0] = 0.0f;
    if (i < BATCH * NPTS) {
        const float x = pc[3 * i + 0];
        const float y = pc[3 * i + 1];
        const float z = pc[3 * i + 2];
        const float sq = fmaf(z, z, fmaf(y, y, x * x));
        cand[i] = make_float4(x, y, z, -0.5f * sq);
    }
}

__global__ __launch_bounds__(1024) void knn_loss_kernel(
    const float*  __restrict__ pc,    // (B, N, 3)
    const float*  __restrict__ mask,  // (B, N, KS)
    const float4* __restrict__ cand,  // (B*N) packed (x,y,z,-0.5|c|^2)
    float* __restrict__ out)          // scalar
{
    // sbuf serves two phases:
    //  phase A (collect): column layout, word = slot*1024 + tid  (each thread
    //   writes/reads ONLY its own column -> race-free without barriers)
    //  phase B (merge): row layout, word = tid*8 + k = (wave*64+q)*8 + k
    __shared__ unsigned sbuf[CAP * NTHREADS];  // 64 KB
    __shared__ int      fidx[QB * KNN];        //  2 KB
    __shared__ float    red[NWAVE];

    const int t = threadIdx.x;
    const int q = t & (QB - 1);   // query slot (lane)
    const int s = t >> 6;         // wave id 0..15 == candidate window id
    const int blk = blockIdx.x;
    const int b  = blk >> 7;              // blk / 128
    const int q0 = (blk & 127) * QB;
    const int qi = q0 + q;                // query index within batch

    const float*  pcb = pc   + (size_t)b * NPTS * 3;
    const float4* cb  = cand + (size_t)b * NPTS;

    const float qx = pcb[qi * 3 + 0];
    const float qy = pcb[qi * 3 + 1];
    const float qz = pcb[qi * 3 + 2];
    const float qs = fmaf(qz, qz, fmaf(qy, qy, qx * qx));

    // pass iff d2 <= R2LOOSE  <=>  tt >= (qs - R2LOOSE)*0.5   (loop-invariant!)
    const float negthr = (qs - R2LOOSE) * 0.5f;

    const unsigned SENT = (__float_as_uint(R2LOOSE) & KEYMASK) | 0x1FFFu;

    // -------- scan: append-only collect, double-buffered uniform loads ------
    const int w0 = __builtin_amdgcn_readfirstlane(s) * CPW;
    const float4* wp = cb + w0;     // wave-uniform window base

    int cnt = 0;
    auto procgroup = [&](const float4* g, int base) {
#pragma unroll
        for (int u = 0; u < GS; ++u) {
            const float4 c = g[u];
            const float tt = fmaf(c.x, qx, fmaf(c.y, qy, fmaf(c.z, qz, c.w)));
            const bool pass = tt >= negthr;
            if (__ballot(pass) != 0ull) {   // wave-uniform branch, ~77% skipped
                const float d2 = fmaxf(fmaf(-2.0f, tt, qs), 0.0f);
                const unsigned key =
                    (__float_as_uint(d2) & KEYMASK) | (unsigned)(base + u);
                if (pass) {
                    const int slot = cnt < (CAP - 1) ? cnt : (CAP - 1);
                    sbuf[slot * NTHREADS + t] = key;
                    ++cnt;
                }
            }
        }
    };

    float4 A[GS], Bv[GS];
#pragma unroll
    for (int u = 0; u < GS; ++u) A[u] = wp[u];
    for (int it = 0; it < NG / 2; ++it) {
        const int gB = 2 * it + 1;
#pragma unroll
        for (int u = 0; u < GS; ++u) Bv[u] = wp[gB * GS + u];
        procgroup(A, w0 + (2 * it) * GS);
        const int gA = (2 * it + 2 < NG) ? 2 * it + 2 : NG - 1;  // last: dummy
#pragma unroll
        for (int u = 0; u < GS; ++u) A[u] = wp[gA * GS + u];
        procgroup(Bv, w0 + gB * GS);
    }

    // -------- stage 1: per-thread sort of its collected keys into top-8 ----
    unsigned md[KNN];
#pragma unroll
    for (int k = 0; k < KNN; ++k) md[k] = SENT;
    const int m = cnt < CAP ? cnt : CAP;
    for (int k = 0; k < m; ++k) {          // divergent, avg ~2.2 iterations
        unsigned ky = sbuf[k * NTHREADS + t];
#pragma unroll
        for (int i = 0; i < KNN; ++i) {
            const unsigned mn = min(ky, md[i]);
            const unsigned mx = max(ky, md[i]);
            md[i] = mn; ky = mx;
        }
    }
    __syncthreads();   // all appends + self-reads done before relayout

    // publish sorted top-8 (row layout, b128)
    {
        uint4* bp = (uint4*)&sbuf[t * KNN];
        bp[0] = make_uint4(md[0], md[1], md[2], md[3]);
        bp[1] = make_uint4(md[4], md[5], md[6], md[7]);
    }
    __syncthreads();

    // -------- stage 2: two-wave tree merge -----------------------------
    if (s == 1) {
        // wave 1: merge windows 8..15 from LDS (reset own md first)
#pragma unroll
        for (int k = 0; k < KNN; ++k) md[k] = SENT;
        for (int l = 8; l < 16; ++l) {
            const uint4* lp = (const uint4*)&sbuf[(l * QB + q) * KNN];
            const uint4 r0 = lp[0], r1 = lp[1];
            const unsigned tk[8] = {r0.x, r0.y, r0.z, r0.w,
                                    r1.x, r1.y, r1.z, r1.w};
#pragma unroll
            for (int k = 0; k < 8; ++k) {
                unsigned ky = tk[k];
                if (ky < md[KNN - 1]) {
#pragma unroll
                    for (int i = 0; i < KNN; ++i) {
                        const unsigned mn = min(ky, md[i]);
                        const unsigned mx = max(ky, md[i]);
                        md[i] = mn; ky = mx;
                    }
                }
            }
        }
        // deposit merged result in window-8's (now consumed) row slots
        uint4* bp = (uint4*)&sbuf[(8 * QB + q) * KNN];
        bp[0] = make_uint4(md[0], md[1], md[2], md[3]);
        bp[1] = make_uint4(md[4], md[5], md[6], md[7]);
    } else if (s == 0) {
        // wave 0: merge windows 1..7 into own md (= window 0)
        for (int l = 1; l < 8; ++l) {
            const uint4* lp = (const uint4*)&sbuf[(l * QB + q) * KNN];
            const uint4 r0 = lp[0], r1 = lp[1];
            const unsigned tk[8] = {r0.x, r0.y, r0.z, r0.w,
                                    r1.x, r1.y, r1.z, r1.w};
#pragma unroll
            for (int k = 0; k < 8; ++k) {
                unsigned ky = tk[k];
                if (ky < md[KNN - 1]) {
#pragma unroll
                    for (int i = 0; i < KNN; ++i) {
                        const unsigned mn = min(ky, md[i]);
                        const unsigned mx = max(ky, md[i]);
                        md[i] = mn; ky = mx;
                    }
                }
            }
        }
    }
    __syncthreads();

    // -------- final: wave 0 folds wave 1's result, radius test, fidx --------
    if (s == 0) {
        const uint4* lp = (const uint4*)&sbuf[(8 * QB + q) * KNN];
        const uint4 r0 = lp[0], r1 = lp[1];
        const unsigned tk[8] = {r0.x, r0.y, r0.z, r0.w,
                                r1.x, r1.y, r1.z, r1.w};
#pragma unroll
        for (int k = 0; k < 8; ++k) {
            unsigned ky = tk[k];
            if (ky < md[KNN - 1]) {
#pragma unroll
                for (int i = 0; i < KNN; ++i) {
                    const unsigned mn = min(ky, md[i]);
                    const unsigned mx = max(ky, md[i]);
                    md[i] = mn; ky = mx;
                }
            }
        }
#pragma unroll
        for (int k = 0; k < KNN; ++k) {
            const unsigned ky = md[k];
            int nb;
            if (ky >= SENT) {
                nb = qi;  // unfilled -> self (contributes 0, matches ref)
            } else {
                const int ci = (int)(ky & 0x1FFFu);
                // exact d2 in difference form (no truncation bias)
                const float dx = pcb[3 * ci + 0] - qx;
                const float dy = pcb[3 * ci + 1] - qy;
                const float dz = pcb[3 * ci + 2] - qz;
                const float d2 = fmaf(dx, dx, fmaf(dy, dy, dz * dz));
                // reference: idx = where(sqrt(d2) > 0.1, self_idx, idx)
                nb = (sqrtf(d2) > 0.1f) ? qi : ci;
            }
            fidx[q * KNN + k] = nb;
        }
    }
    __syncthreads();

    // -------- loss gather: 1024 threads <-> 64 q x 8 nn x 2 half-rows ------
    const int q2 = t >> 4;
    const int j2 = (t >> 1) & 7;
    const int h  = t & 1;
    const int qg = q0 + q2;
    const int nb = fidx[q2 * KNN + j2];
    const float* mrow = mask + ((size_t)b * NPTS + qg) * KS + h * 8;
    const float* nrow = mask + ((size_t)b * NPTS + nb) * KS + h * 8;
    float acc = 0.0f;
#pragma unroll
    for (int c = 0; c < 8; c += 4) {
        const float4 a = *(const float4*)(mrow + c);
        const float4 v = *(const float4*)(nrow + c);
        acc += fabsf(a.x - v.x) + fabsf(a.y - v.y) +
               fabsf(a.z - v.z) + fabsf(a.w - v.w);
    }

    // block reduction: wave shuffle -> LDS -> one atomic per block
#pragma unroll
    for (int off = 32; off > 0; off >>= 1) acc += __shfl_down(acc, off);
    if ((t & 63) == 0) red[s] = acc;
    __syncthreads();
    if (t == 0) {
        float sum = 0.0f;
#pragma unroll
        for (int i = 0; i < NWAVE; ++i) sum += red[i];
        atomicAdd(out, sum * (1.0f / (BATCH * NPTS * KNN)));
    }
}

extern "C" void kernel_launch(void* const* d_in, const int* in_sizes, int n_in,
                              void* d_out, int out_size, void* d_ws, size_t ws_size,
                              hipStream_t stream) {
    const float* pc   = (const float*)d_in[0];  // (2, 8192, 3)
    const float* mask = (const float*)d_in[1];  // (2, 8192, 16)
    float* out   = (float*)d_out;               // scalar, poisoned 0xAA each call
    float4* cand = (float4*)d_ws;               // 16384 * 16 B = 256 KB scratch

    hipLaunchKernelGGL(pack_kernel, dim3((BATCH * NPTS + 255) / 256), dim3(256),
                       0, stream, pc, cand, out);
    hipLaunchKernelGGL(knn_loss_kernel, dim3(NBLK), dim3(1024), 0, stream,
                       pc, mask, cand, out);
}

// Round 5
// 95.974 us; speedup vs baseline: 4.7000x; 1.0752x over previous
//
#include <hip/hip_runtime.h>
#include <hip/hip_bf16.h>

// Problem constants (fixed by setup_inputs)
#define BATCH 2
#define NPTS  8192
#define KS    16
#define KNN   8
#define R2LOOSE 0.0101f      // loose prefilter ball; exact radius test at end
#define KEYMASK 0xFFFFE000u  // high 19 bits of d2; low 13 bits = sorted pos
#define NCELL   1000         // 10x10x10 grid, cell size 0.1 (= RADIUS)
#define CSTRIDE 1024         // padded per-batch cell-array stride

// Main kernel geometry
#define QB       64                 // queries per block (= wave size)
#define NWAVE    16                 // waves per block (1024 threads)
#define NTHREADS 1024
#define CAP      16                 // collect capacity per thread
#define NBLK     (BATCH * NPTS / QB)   // 256 blocks

__device__ __forceinline__ int cell_of(float x, float y, float z) {
    int cx = (int)(x * 10.0f); cx = cx > 9 ? 9 : cx;
    int cy = (int)(y * 10.0f); cy = cy > 9 ? 9 : cy;
    int cz = (int)(z * 10.0f); cz = cz > 9 ? 9 : cz;
    return (cx * 10 + cy) * 10 + cz;
}

// ---- grid build ------------------------------------------------------------
__global__ void init_kernel(int* cfill, float* out) {
    const int t = threadIdx.x;
    if (t == 0) out[0] = 0.0f;
    cfill[t] = 0;
    cfill[t + CSTRIDE] = 0;
}

__global__ void count_kernel(const float* __restrict__ pc, int* cfill) {
    const int i = blockIdx.x * 1024 + threadIdx.x;   // 16 blocks -> 16384
    const float x = pc[3 * i], y = pc[3 * i + 1], z = pc[3 * i + 2];
    const int b = i >> 13;
    atomicAdd(&cfill[b * CSTRIDE + cell_of(x, y, z)], 1);
}

// exclusive prefix per batch; writes cell_start and resets cfill to starts
__global__ __launch_bounds__(1024) void scan_kernel(int* cfill, int* cstart) {
    __shared__ int arr[1024];
    const int b = blockIdx.x, t = threadIdx.x;
    const int cnt = cfill[b * CSTRIDE + t];   // t >= NCELL slots are 0
    arr[t] = cnt;
    __syncthreads();
    for (int off = 1; off < 1024; off <<= 1) {
        const int v = (t >= off) ? arr[t - off] : 0;
        __syncthreads();
        arr[t] += v;
        __syncthreads();
    }
    const int excl = arr[t] - cnt;
    cstart[b * CSTRIDE + t] = excl;
    cfill[b * CSTRIDE + t]  = excl;
}

__global__ void scatter_kernel(const float* __restrict__ pc,
                               float4* __restrict__ cs,
                               int* __restrict__ sidx, int* cfill) {
    const int i = blockIdx.x * 1024 + threadIdx.x;
    const float x = pc[3 * i], y = pc[3 * i + 1], z = pc[3 * i + 2];
    const int b = i >> 13;
    const float sq = fmaf(z, z, fmaf(y, y, x * x));
    const int pos = atomicAdd(&cfill[b * CSTRIDE + cell_of(x, y, z)], 1);
    cs[b * NPTS + pos]   = make_float4(x, y, z, -0.5f * sq);
    sidx[b * NPTS + pos] = i & (NPTS - 1);   // orig within-batch index
}

// ---- fused knn + loss ------------------------------------------------------
__global__ __launch_bounds__(1024) void knn_loss_kernel(
    const float4* __restrict__ cs,     // cell-sorted (x,y,z,-0.5|c|^2)
    const int*    __restrict__ sidx,   // sorted pos -> orig idx
    const int*    __restrict__ cstart, // per-batch cell starts (padded 1024)
    const float*  __restrict__ mask,   // (B, N, KS) in ORIGINAL order
    float* __restrict__ out)
{
    __shared__ unsigned sbuf[CAP * NTHREADS];  // 64 KB collect/merge buffer
    __shared__ int      fidx[QB * KNN];        //  2 KB final orig neighbor idx
    __shared__ int      qid[QB];               // orig idx of block's queries
    __shared__ float    red[NWAVE];

    const int t = threadIdx.x;
    const int q = t & (QB - 1);   // query slot (lane)
    const int s = t >> 6;         // wave id 0..15
    const int blk = blockIdx.x;
    const int b  = blk >> 7;
    const int q0 = (blk & 127) * QB;      // sorted-position base
    const int qpos = q0 + q;

    const float4* csb = cs + b * NPTS;
    const float4 qc = csb[qpos];
    const int    qi = sidx[b * NPTS + qpos];
    if (s == 0) qid[q] = qi;

    const float qx = qc.x, qy = qc.y, qz = qc.z;
    const float qs = -2.0f * qc.w;                 // exact (power of 2)
    const float negthr = (qs - R2LOOSE) * 0.5f;    // pass iff tt >= negthr
    const unsigned SENT = (__float_as_uint(R2LOOSE) & KEYMASK) | 0x1FFFu;

    // block's contiguous lex-cell run (all waves compute identically)
    int lex = cell_of(qx, qy, qz);
    int cmn = lex, cmx = lex;
#pragma unroll
    for (int off = 32; off; off >>= 1) {
        cmn = min(cmn, __shfl_xor(cmn, off));
        cmx = max(cmx, __shfl_xor(cmx, off));
    }
    const int cfirst = __builtin_amdgcn_readfirstlane(cmn);
    const int clast  = __builtin_amdgcn_readfirstlane(cmx);

    // union of 27-neighborhoods of run cells = 9 lex intervals; merge them.
    // (y/x wrap adds spurious far cells -> fail prefilter; never misses one.)
    int plo[9], phi[9];
    int nr = 0;
    {
        const int offs[9] = {-110, -100, -90, -10, 0, 10, 90, 100, 110};
        int mlo[9], mhi[9];
#pragma unroll
        for (int i = 0; i < 9; ++i) {
            int lo = cfirst + offs[i] - 1; if (lo < 0) lo = 0;
            int hi = clast  + offs[i] + 1; if (hi > NCELL - 1) hi = NCELL - 1;
            if (lo > hi) continue;
            if (nr && lo <= mhi[nr - 1] + 1) {
                if (hi > mhi[nr - 1]) mhi[nr - 1] = hi;
            } else { mlo[nr] = lo; mhi[nr] = hi; ++nr; }
        }
        const int* csp = cstart + b * CSTRIDE;
        for (int r = 0; r < nr; ++r) {
            plo[r] = csp[mlo[r]];
            phi[r] = csp[mhi[r] + 1];
        }
    }
    int cum[10]; cum[0] = 0;
    for (int r = 0; r < nr; ++r) cum[r + 1] = cum[r] + (phi[r] - plo[r]);
    const int C = cum[nr];
    const int G = (C + NWAVE - 1) / NWAVE;
    const int vlo = s * G;
    const int vhi = min(vlo + G, C);

    // append-only collect over this wave's slice of the candidate list
    int cnt = 0;
    auto EVAL = [&](const float4& c, int spos) {
        const float tt = fmaf(c.x, qx, fmaf(c.y, qy, fmaf(c.z, qz, c.w)));
        if (tt >= negthr) {                 // per-lane predicated, ~5%/lane
            const float d2 = fmaxf(fmaf(-2.0f, tt, qs), 0.0f);
            const unsigned key =
                (__float_as_uint(d2) & KEYMASK) | (unsigned)spos;
            const int slot = cnt < (CAP - 1) ? cnt : (CAP - 1);
            sbuf[slot * NTHREADS + t] = key;
            ++cnt;
        }
    };
    for (int r = 0; r < nr; ++r) {
        int a = vlo - cum[r]; if (a < 0) a = 0;
        int e = vhi - cum[r];
        const int len = phi[r] - plo[r];
        if (e > len) e = len;
        const int base = plo[r];           // wave-uniform -> s_load fetches
        int j = a;
        for (; j + 4 <= e; j += 4) {
            const float4 c0 = csb[base + j];
            const float4 c1 = csb[base + j + 1];
            const float4 c2 = csb[base + j + 2];
            const float4 c3 = csb[base + j + 3];
            EVAL(c0, base + j);     EVAL(c1, base + j + 1);
            EVAL(c2, base + j + 2); EVAL(c3, base + j + 3);
        }
        for (; j < e; ++j) { const float4 c0 = csb[base + j]; EVAL(c0, base + j); }
    }

    // per-thread sort of collected keys (avg ~2) into top-8
    unsigned md[KNN];
#pragma unroll
    for (int k = 0; k < KNN; ++k) md[k] = SENT;
    const int m = cnt < CAP ? cnt : CAP;
    for (int k = 0; k < m; ++k) {
        unsigned ky = sbuf[k * NTHREADS + t];
#pragma unroll
        for (int i = 0; i < KNN; ++i) {
            const unsigned mn = min(ky, md[i]);
            const unsigned mx = max(ky, md[i]);
            md[i] = mn; ky = mx;
        }
    }
    __syncthreads();   // collect reads done before row-relayout

    {   // publish sorted top-8 (row layout)
        uint4* bp = (uint4*)&sbuf[t * KNN];
        bp[0] = make_uint4(md[0], md[1], md[2], md[3]);
        bp[1] = make_uint4(md[4], md[5], md[6], md[7]);
    }
    __syncthreads();

    // two-wave tree merge of the 16 partial lists per query
    if (s == 1) {
#pragma unroll
        for (int k = 0; k < KNN; ++k) md[k] = SENT;
        for (int l = 8; l < 16; ++l) {
            const uint4* lp = (const uint4*)&sbuf[(l * QB + q) * KNN];
            const uint4 r0 = lp[0], r1 = lp[1];
            const unsigned tk[8] = {r0.x, r0.y, r0.z, r0.w,
                                    r1.x, r1.y, r1.z, r1.w};
#pragma unroll
            for (int k = 0; k < 8; ++k) {
                unsigned ky = tk[k];
                if (ky < md[KNN - 1]) {
#pragma unroll
                    for (int i = 0; i < KNN; ++i) {
                        const unsigned mn = min(ky, md[i]);
                        const unsigned mx = max(ky, md[i]);
                        md[i] = mn; ky = mx;
                    }
                }
            }
        }
        uint4* bp = (uint4*)&sbuf[(8 * QB + q) * KNN];
        bp[0] = make_uint4(md[0], md[1], md[2], md[3]);
        bp[1] = make_uint4(md[4], md[5], md[6], md[7]);
    } else if (s == 0) {
        for (int l = 1; l < 8; ++l) {
            const uint4* lp = (const uint4*)&sbuf[(l * QB + q) * KNN];
            const uint4 r0 = lp[0], r1 = lp[1];
            const unsigned tk[8] = {r0.x, r0.y, r0.z, r0.w,
                                    r1.x, r1.y, r1.z, r1.w};
#pragma unroll
            for (int k = 0; k < 8; ++k) {
                unsigned ky = tk[k];
                if (ky < md[KNN - 1]) {
#pragma unroll
                    for (int i = 0; i < KNN; ++i) {
                        const unsigned mn = min(ky, md[i]);
                        const unsigned mx = max(ky, md[i]);
                        md[i] = mn; ky = mx;
                    }
                }
            }
        }
    }
    __syncthreads();

    // wave 0: fold wave 1's half, exact radius test, emit orig-index fidx
    if (s == 0) {
        const uint4* lp = (const uint4*)&sbuf[(8 * QB + q) * KNN];
        const uint4 r0 = lp[0], r1 = lp[1];
        const unsigned tk[8] = {r0.x, r0.y, r0.z, r0.w,
                                r1.x, r1.y, r1.z, r1.w};
#pragma unroll
        for (int k = 0; k < 8; ++k) {
            unsigned ky = tk[k];
            if (ky < md[KNN - 1]) {
#pragma unroll
                for (int i = 0; i < KNN; ++i) {
                    const unsigned mn = min(ky, md[i]);
                    const unsigned mx = max(ky, md[i]);
                    md[i] = mn; ky = mx;
                }
            }
        }
#pragma unroll
        for (int k = 0; k < KNN; ++k) {
            const unsigned ky = md[k];
            int nb;
            if (ky >= SENT) {
                nb = qi;  // unfilled -> self (contributes 0, matches ref)
            } else {
                const int sp = (int)(ky & 0x1FFFu);
                const float4 cc = csb[sp];
                const float dx = cc.x - qx;
                const float dy = cc.y - qy;
                const float dz = cc.z - qz;
                const float d2 = fmaf(dx, dx, fmaf(dy, dy, dz * dz));
                // reference: idx = where(sqrt(d2) > 0.1, self_idx, idx)
                nb = (sqrtf(d2) > 0.1f) ? qi : sidx[b * NPTS + sp];
            }
            fidx[q * KNN + k] = nb;
        }
    }
    __syncthreads();

    // loss gather: 1024 threads <-> 64 q x 8 nn x 2 half-rows (orig indices)
    const int q2 = t >> 4;
    const int j2 = (t >> 1) & 7;
    const int h  = t & 1;
    const int qg = qid[q2];
    const int nb = fidx[q2 * KNN + j2];
    const float* mrow = mask + ((size_t)b * NPTS + qg) * KS + h * 8;
    const float* nrow = mask + ((size_t)b * NPTS + nb) * KS + h * 8;
    float acc = 0.0f;
#pragma unroll
    for (int c = 0; c < 8; c += 4) {
        const float4 a = *(const float4*)(mrow + c);
        const float4 v = *(const float4*)(nrow + c);
        acc += fabsf(a.x - v.x) + fabsf(a.y - v.y) +
               fabsf(a.z - v.z) + fabsf(a.w - v.w);
    }

    // block reduction: wave shuffle -> LDS -> one atomic per block
#pragma unroll
    for (int off = 32; off > 0; off >>= 1) acc += __shfl_down(acc, off);
    if ((t & 63) == 0) red[s] = acc;
    __syncthreads();
    if (t == 0) {
        float sum = 0.0f;
#pragma unroll
        for (int i = 0; i < NWAVE; ++i) sum += red[i];
        atomicAdd(out, sum * (1.0f / (BATCH * NPTS * KNN)));
    }
}

extern "C" void kernel_launch(void* const* d_in, const int* in_sizes, int n_in,
                              void* d_out, int out_size, void* d_ws, size_t ws_size,
                              hipStream_t stream) {
    const float* pc   = (const float*)d_in[0];  // (2, 8192, 3)
    const float* mask = (const float*)d_in[1];  // (2, 8192, 16)
    float* out = (float*)d_out;                 // scalar, poisoned 0xAA each call

    // workspace layout (344 KB total)
    float4* cs     = (float4*)d_ws;                              // 256 KB
    int*    sidx   = (int*)((char*)d_ws + 262144);               //  64 KB
    int*    cstart = (int*)((char*)d_ws + 327680);               //   8 KB
    int*    cfill  = (int*)((char*)d_ws + 335872);               //   8 KB

    hipLaunchKernelGGL(init_kernel,    dim3(1),  dim3(1024), 0, stream, cfill, out);
    hipLaunchKernelGGL(count_kernel,   dim3(16), dim3(1024), 0, stream, pc, cfill);
    hipLaunchKernelGGL(scan_kernel,    dim3(2),  dim3(1024), 0, stream, cfill, cstart);
    hipLaunchKernelGGL(scatter_kernel, dim3(16), dim3(1024), 0, stream, pc, cs, sidx, cfill);
    hipLaunchKernelGGL(knn_loss_kernel, dim3(NBLK), dim3(1024), 0, stream,
                       cs, sidx, cstart, mask, out);
}

// Round 6
// 90.252 us; speedup vs baseline: 4.9979x; 1.0634x over previous
//
#include <hip/hip_runtime.h>
#include <hip/hip_bf16.h>

// Problem constants (fixed by setup_inputs)
#define BATCH 2
#define NPTS  8192
#define KS    16
#define KNN   8
#define R2LOOSE 0.0101f      // loose prefilter ball; exact radius test at end
#define KEYMASK 0xFFFFE000u  // high 19 bits of d2; low 13 bits = sorted pos
#define NCELL   1000         // 10x10x10 grid, cell size 0.1 (= RADIUS)
#define CSTRIDE 1024         // padded per-batch cell-array stride

// Main kernel geometry
#define QB       64                 // queries per block (= wave size)
#define NWAVE    8                  // waves per block (512 threads)
#define NTHREADS 512
#define CAP      32                 // collect capacity per thread
#define NBLK     (BATCH * NPTS / QB)   // 256 blocks

__device__ __forceinline__ int cell_of(float x, float y, float z) {
    int cx = (int)(x * 10.0f); cx = cx > 9 ? 9 : cx;
    int cy = (int)(y * 10.0f); cy = cy > 9 ? 9 : cy;
    int cz = (int)(z * 10.0f); cz = cz > 9 ? 9 : cz;
    return (cx * 10 + cy) * 10 + cz;
}

// ---- fused grid build: one block per batch ---------------------------------
// zero counters -> LDS-atomic count -> LDS scan -> scatter (coords from regs)
#define PPT (NPTS / 1024)   // 8 points per thread
__global__ __launch_bounds__(1024) void build_kernel(
    const float* __restrict__ pc,
    float4* __restrict__ cs, int* __restrict__ sidx,
    int* __restrict__ cstart, float* __restrict__ out)
{
    __shared__ int cnt_s[1024];   // per-cell counts, then fill cursors
    __shared__ int scan_s[1024];

    const int b = blockIdx.x, t = threadIdx.x;
    if (b == 0 && t == 0) out[0] = 0.0f;
    cnt_s[t] = 0;
    __syncthreads();

    const float* p = pc + (size_t)b * NPTS * 3;
    float px[PPT], py[PPT], pz[PPT];
    int   pcell[PPT];
#pragma unroll
    for (int u = 0; u < PPT; ++u) {
        const int i = t + u * 1024;           // coalesced across the block
        px[u] = p[3 * i];
        py[u] = p[3 * i + 1];
        pz[u] = p[3 * i + 2];
        pcell[u] = cell_of(px[u], py[u], pz[u]);
        atomicAdd(&cnt_s[pcell[u]], 1);
    }
    __syncthreads();

    // exclusive scan over 1024 cells (cells >= NCELL have count 0)
    const int myc = cnt_s[t];
    scan_s[t] = myc;
    __syncthreads();
    for (int off = 1; off < 1024; off <<= 1) {
        const int v = (t >= off) ? scan_s[t - off] : 0;
        __syncthreads();
        scan_s[t] += v;
        __syncthreads();
    }
    const int excl = scan_s[t] - myc;
    cstart[b * CSTRIDE + t] = excl;
    cnt_s[t] = excl;                          // reuse as fill cursor
    __syncthreads();

    // scatter into cell-sorted order
#pragma unroll
    for (int u = 0; u < PPT; ++u) {
        const int pos = atomicAdd(&cnt_s[pcell[u]], 1);
        const float sq = fmaf(pz[u], pz[u], fmaf(py[u], py[u], px[u] * px[u]));
        cs[b * NPTS + pos]   = make_float4(px[u], py[u], pz[u], -0.5f * sq);
        sidx[b * NPTS + pos] = t + u * 1024;  // orig within-batch index
    }
}

// ---- fused knn + loss ------------------------------------------------------
__global__ __launch_bounds__(512) void knn_loss_kernel(
    const float4* __restrict__ cs,     // cell-sorted (x,y,z,-0.5|c|^2)
    const int*    __restrict__ sidx,   // sorted pos -> orig idx
    const int*    __restrict__ cstart, // per-batch cell starts (padded 1024)
    const float*  __restrict__ mask,   // (B, N, KS) in ORIGINAL order
    float* __restrict__ out)
{
    // phase A (collect): column layout, word = slot*512 + tid (own column only)
    // phase B (merge):  row layout,    word = tid*8 + k
    __shared__ unsigned sbuf[CAP * NTHREADS];  // 64 KB
    __shared__ int      fidx[QB * KNN];        //  2 KB
    __shared__ int      qid[QB];
    __shared__ float    red[NWAVE];

    const int t = threadIdx.x;
    const int q = t & (QB - 1);   // query slot (lane)
    const int s = t >> 6;         // wave id 0..7
    const int blk = blockIdx.x;
    const int b  = blk >> 7;
    const int q0 = (blk & 127) * QB;      // sorted-position base
    const int qpos = q0 + q;

    const float4* csb = cs + b * NPTS;
    const float4 qc = csb[qpos];
    const int    qi = sidx[b * NPTS + qpos];
    if (s == 0) qid[q] = qi;

    const float qx = qc.x, qy = qc.y, qz = qc.z;
    const float qs = -2.0f * qc.w;                 // exact (power of 2)
    const float negthr = (qs - R2LOOSE) * 0.5f;    // pass iff tt >= negthr
    const unsigned SENT = (__float_as_uint(R2LOOSE) & KEYMASK) | 0x1FFFu;

    // block's contiguous lex-cell run (all waves compute identically)
    int lex = cell_of(qx, qy, qz);
    int cmn = lex, cmx = lex;
#pragma unroll
    for (int off = 32; off; off >>= 1) {
        cmn = min(cmn, __shfl_xor(cmn, off));
        cmx = max(cmx, __shfl_xor(cmx, off));
    }
    const int cfirst = __builtin_amdgcn_readfirstlane(cmn);
    const int clast  = __builtin_amdgcn_readfirstlane(cmx);

    // union of 27-neighborhoods of run cells = 9 lex intervals; merge them.
    // (y/x wrap adds spurious far cells -> fail prefilter; never misses one.)
    int plo[9], phi[9];
    int nr = 0;
    {
        const int offs[9] = {-110, -100, -90, -10, 0, 10, 90, 100, 110};
        int mlo[9], mhi[9];
#pragma unroll
        for (int i = 0; i < 9; ++i) {
            int lo = cfirst + offs[i] - 1; if (lo < 0) lo = 0;
            int hi = clast  + offs[i] + 1; if (hi > NCELL - 1) hi = NCELL - 1;
            if (lo > hi) continue;
            if (nr && lo <= mhi[nr - 1] + 1) {
                if (hi > mhi[nr - 1]) mhi[nr - 1] = hi;
            } else { mlo[nr] = lo; mhi[nr] = hi; ++nr; }
        }
        const int* csp = cstart + b * CSTRIDE;
        for (int r = 0; r < nr; ++r) {
            plo[r] = csp[mlo[r]];
            phi[r] = csp[mhi[r] + 1];
        }
    }
    int cum[10]; cum[0] = 0;
    for (int r = 0; r < nr; ++r) cum[r + 1] = cum[r] + (phi[r] - plo[r]);
    const int C = cum[nr];
    const int G = (C + NWAVE - 1) / NWAVE;
    const int vlo = s * G;
    const int vhi = min(vlo + G, C);

    // append-only collect over this wave's slice of the candidate list
    int cnt = 0;
    auto EVAL = [&](const float4& c, int spos) {
        const float tt = fmaf(c.x, qx, fmaf(c.y, qy, fmaf(c.z, qz, c.w)));
        if (tt >= negthr) {                 // per-lane predicated, rare
            const float d2 = fmaxf(fmaf(-2.0f, tt, qs), 0.0f);
            const unsigned key =
                (__float_as_uint(d2) & KEYMASK) | (unsigned)spos;
            const int slot = cnt < (CAP - 1) ? cnt : (CAP - 1);
            sbuf[slot * NTHREADS + t] = key;
            ++cnt;
        }
    };
    for (int r = 0; r < nr; ++r) {
        int a = vlo - cum[r]; if (a < 0) a = 0;
        int e = vhi - cum[r];
        const int len = phi[r] - plo[r];
        if (e > len) e = len;
        const int base = plo[r];           // wave-uniform -> s_load fetches
        int j = a;
        for (; j + 4 <= e; j += 4) {
            const float4 c0 = csb[base + j];
            const float4 c1 = csb[base + j + 1];
            const float4 c2 = csb[base + j + 2];
            const float4 c3 = csb[base + j + 3];
            EVAL(c0, base + j);     EVAL(c1, base + j + 1);
            EVAL(c2, base + j + 2); EVAL(c3, base + j + 3);
        }
        for (; j < e; ++j) { const float4 c0 = csb[base + j]; EVAL(c0, base + j); }
    }

    // per-thread sort of collected keys (avg ~4) into top-8
    unsigned md[KNN];
#pragma unroll
    for (int k = 0; k < KNN; ++k) md[k] = SENT;
    const int m = cnt < CAP ? cnt : CAP;
    for (int k = 0; k < m; ++k) {
        unsigned ky = sbuf[k * NTHREADS + t];
#pragma unroll
        for (int i = 0; i < KNN; ++i) {
            const unsigned mn = min(ky, md[i]);
            const unsigned mx = max(ky, md[i]);
            md[i] = mn; ky = mx;
        }
    }
    __syncthreads();   // collect reads done before row-relayout

    {   // publish sorted top-8 (row layout)
        uint4* bp = (uint4*)&sbuf[t * KNN];
        bp[0] = make_uint4(md[0], md[1], md[2], md[3]);
        bp[1] = make_uint4(md[4], md[5], md[6], md[7]);
    }
    __syncthreads();

    // wave 0: single-stage merge of the 8 partial lists per query,
    // exact radius test, emit orig-index fidx
    if (s == 0) {
        for (int l = 1; l < NWAVE; ++l) {
            const uint4* lp = (const uint4*)&sbuf[(l * QB + q) * KNN];
            const uint4 r0 = lp[0], r1 = lp[1];
            const unsigned tk[8] = {r0.x, r0.y, r0.z, r0.w,
                                    r1.x, r1.y, r1.z, r1.w};
#pragma unroll
            for (int k = 0; k < 8; ++k) {
                unsigned ky = tk[k];
                if (ky < md[KNN - 1]) {    // sentinel skip
#pragma unroll
                    for (int i = 0; i < KNN; ++i) {
                        const unsigned mn = min(ky, md[i]);
                        const unsigned mx = max(ky, md[i]);
                        md[i] = mn; ky = mx;
                    }
                }
            }
        }
#pragma unroll
        for (int k = 0; k < KNN; ++k) {
            const unsigned ky = md[k];
            int nb;
            if (ky >= SENT) {
                nb = qi;  // unfilled -> self (contributes 0, matches ref)
            } else {
                const int sp = (int)(ky & 0x1FFFu);
                const float4 cc = csb[sp];
                const float dx = cc.x - qx;
                const float dy = cc.y - qy;
                const float dz = cc.z - qz;
                const float d2 = fmaf(dx, dx, fmaf(dy, dy, dz * dz));
                // reference: idx = where(sqrt(d2) > 0.1, self_idx, idx)
                nb = (sqrtf(d2) > 0.1f) ? qi : sidx[b * NPTS + sp];
            }
            fidx[q * KNN + k] = nb;
        }
    }
    __syncthreads();

    // loss gather: 512 threads <-> 64 q x 8 nn, full 16-ch rows
    const int q2 = t >> 3;
    const int j2 = t & 7;
    const int qg = qid[q2];
    const int nb = fidx[q2 * KNN + j2];
    const float* mrow = mask + ((size_t)b * NPTS + qg) * KS;
    const float* nrow = mask + ((size_t)b * NPTS + nb) * KS;
    float acc = 0.0f;
#pragma unroll
    for (int c = 0; c < KS; c += 4) {
        const float4 a = *(const float4*)(mrow + c);
        const float4 v = *(const float4*)(nrow + c);
        acc += fabsf(a.x - v.x) + fabsf(a.y - v.y) +
               fabsf(a.z - v.z) + fabsf(a.w - v.w);
    }

    // block reduction: wave shuffle -> LDS -> one atomic per block
#pragma unroll
    for (int off = 32; off > 0; off >>= 1) acc += __shfl_down(acc, off);
    if ((t & 63) == 0) red[s] = acc;
    __syncthreads();
    if (t == 0) {
        float sum = 0.0f;
#pragma unroll
        for (int i = 0; i < NWAVE; ++i) sum += red[i];
        atomicAdd(out, sum * (1.0f / (BATCH * NPTS * KNN)));
    }
}

extern "C" void kernel_launch(void* const* d_in, const int* in_sizes, int n_in,
                              void* d_out, int out_size, void* d_ws, size_t ws_size,
                              hipStream_t stream) {
    const float* pc   = (const float*)d_in[0];  // (2, 8192, 3)
    const float* mask = (const float*)d_in[1];  // (2, 8192, 16)
    float* out = (float*)d_out;                 // scalar, poisoned 0xAA each call

    // workspace layout (336 KB used)
    float4* cs     = (float4*)d_ws;                              // 256 KB
    int*    sidx   = (int*)((char*)d_ws + 262144);               //  64 KB
    int*    cstart = (int*)((char*)d_ws + 327680);               //   8 KB

    hipLaunchKernelGGL(build_kernel, dim3(BATCH), dim3(1024), 0, stream,
                       pc, cs, sidx, cstart, out);
    hipLaunchKernelGGL(knn_loss_kernel, dim3(NBLK), dim3(512), 0, stream,
                       cs, sidx, cstart, mask, out);
}

// Round 7
// 89.213 us; speedup vs baseline: 5.0562x; 1.0117x over previous
//
#include <hip/hip_runtime.h>
#include <hip/hip_bf16.h>

// Problem constants (fixed by setup_inputs)
#define BATCH 2
#define NPTS  8192
#define KS    16
#define KNN   8
#define R2LOOSE 0.0101f      // loose prefilter ball; exact radius test at end
#define KEYMASK 0xFFFFE000u  // high 19 bits of d2; low 13 bits = sorted pos
#define NCELL   1000         // 10x10x10 grid, cell size 0.1 (= RADIUS)
#define CSTRIDE 1024         // padded per-batch cell-array stride

// Main kernel geometry
#define QB       64                 // queries per block (= wave size)
#define NWAVE    8                  // waves per block (512 threads)
#define NTHREADS 512
#define CAP      32                 // collect capacity per thread
#define NBLK     (BATCH * NPTS / QB)   // 256 blocks

__device__ __forceinline__ int cell_of(float x, float y, float z) {
    int cx = (int)(x * 10.0f); cx = cx > 9 ? 9 : cx;
    int cy = (int)(y * 10.0f); cy = cy > 9 ? 9 : cy;
    int cz = (int)(z * 10.0f); cz = cz > 9 ? 9 : cz;
    return (cx * 10 + cy) * 10 + cz;
}

// ---- grid build (parallel, small kernels) ----------------------------------
__global__ void count_kernel(const float* __restrict__ pc, int* cfill) {
    const int i = blockIdx.x * 1024 + threadIdx.x;   // 16 blocks -> 16384
    const float x = pc[3 * i], y = pc[3 * i + 1], z = pc[3 * i + 2];
    const int b = i >> 13;
    atomicAdd(&cfill[b * CSTRIDE + cell_of(x, y, z)], 1);
}

// exclusive prefix per batch; writes cstart, resets cfill to cursors,
// zeroes the output scalar (runs before main in-stream).
__global__ __launch_bounds__(1024) void scan_kernel(int* cfill, int* cstart,
                                                    float* out) {
    __shared__ int arr[1024];
    const int b = blockIdx.x, t = threadIdx.x;
    if (b == 0 && t == 0) out[0] = 0.0f;
    const int cnt = cfill[b * CSTRIDE + t];   // t >= NCELL slots are 0
    arr[t] = cnt;
    __syncthreads();
    for (int off = 1; off < 1024; off <<= 1) {
        const int v = (t >= off) ? arr[t - off] : 0;
        __syncthreads();
        arr[t] += v;
        __syncthreads();
    }
    const int excl = arr[t] - cnt;
    cstart[b * CSTRIDE + t] = excl;
    cfill[b * CSTRIDE + t]  = excl;
}

__global__ void scatter_kernel(const float* __restrict__ pc,
                               float4* __restrict__ cs,
                               int* __restrict__ sidx, int* cfill) {
    const int i = blockIdx.x * 1024 + threadIdx.x;   // 16 blocks -> 16384
    const float x = pc[3 * i], y = pc[3 * i + 1], z = pc[3 * i + 2];
    const int b = i >> 13;
    const float sq = fmaf(z, z, fmaf(y, y, x * x));
    const int pos = atomicAdd(&cfill[b * CSTRIDE + cell_of(x, y, z)], 1);
    cs[b * NPTS + pos]   = make_float4(x, y, z, -0.5f * sq);
    sidx[b * NPTS + pos] = i & (NPTS - 1);   // orig within-batch index
}

// ---- fused knn + loss ------------------------------------------------------
__global__ __launch_bounds__(512) void knn_loss_kernel(
    const float4* __restrict__ cs,     // cell-sorted (x,y,z,-0.5|c|^2)
    const int*    __restrict__ sidx,   // sorted pos -> orig idx
    const int*    __restrict__ cstart, // per-batch cell starts (padded 1024)
    const float*  __restrict__ mask,   // (B, N, KS) in ORIGINAL order
    float* __restrict__ out)
{
    // phase A (collect): column layout, word = slot*512 + tid (own column only)
    // phase B (merge):  row layout,    word = tid*8 + k
    __shared__ unsigned sbuf[CAP * NTHREADS];  // 64 KB
    __shared__ int      fidx[QB * KNN];        //  2 KB
    __shared__ int      qid[QB];
    __shared__ float    red[NWAVE];

    const int t = threadIdx.x;
    const int q = t & (QB - 1);   // query slot (lane)
    const int s = t >> 6;         // wave id 0..7
    // wave-uniform copy of s: roots the uniformity chain so candidate
    // fetches scalarize to s_load (R4 evidence: SGPR=64/VGPR=20)
    const int su = __builtin_amdgcn_readfirstlane(s);
    const int blk = blockIdx.x;
    const int b  = blk >> 7;
    const int q0 = (blk & 127) * QB;      // sorted-position base
    const int qpos = q0 + q;

    const float4* csb = cs + b * NPTS;
    const float4 qc = csb[qpos];
    const int    qi = sidx[b * NPTS + qpos];
    if (s == 0) qid[q] = qi;

    const float qx = qc.x, qy = qc.y, qz = qc.z;
    const float qs = -2.0f * qc.w;                 // exact (power of 2)
    const float negthr = (qs - R2LOOSE) * 0.5f;    // pass iff tt >= negthr
    const unsigned SENT = (__float_as_uint(R2LOOSE) & KEYMASK) | 0x1FFFu;

    // block's contiguous lex-cell run (all waves compute identically)
    int lex = cell_of(qx, qy, qz);
    int cmn = lex, cmx = lex;
#pragma unroll
    for (int off = 32; off; off >>= 1) {
        cmn = min(cmn, __shfl_xor(cmn, off));
        cmx = max(cmx, __shfl_xor(cmx, off));
    }
    const int cfirst = __builtin_amdgcn_readfirstlane(cmn);
    const int clast  = __builtin_amdgcn_readfirstlane(cmx);

    // union of 27-neighborhoods of run cells = 9 lex intervals; merge them.
    // (y/x wrap adds spurious far cells -> fail prefilter; never misses one.)
    int plo[9], phi[9];
    int nr = 0;
    {
        const int offs[9] = {-110, -100, -90, -10, 0, 10, 90, 100, 110};
        int mlo[9], mhi[9];
#pragma unroll
        for (int i = 0; i < 9; ++i) {
            int lo = cfirst + offs[i] - 1; if (lo < 0) lo = 0;
            int hi = clast  + offs[i] + 1; if (hi > NCELL - 1) hi = NCELL - 1;
            if (lo > hi) continue;
            if (nr && lo <= mhi[nr - 1] + 1) {
                if (hi > mhi[nr - 1]) mhi[nr - 1] = hi;
            } else { mlo[nr] = lo; mhi[nr] = hi; ++nr; }
        }
        const int* csp = cstart + b * CSTRIDE;
        for (int r = 0; r < nr; ++r) {
            plo[r] = csp[mlo[r]];
            phi[r] = csp[mhi[r] + 1];
        }
    }
    int cum[10]; cum[0] = 0;
    for (int r = 0; r < nr; ++r) cum[r + 1] = cum[r] + (phi[r] - plo[r]);
    const int C = cum[nr];
    const int G = (C + NWAVE - 1) / NWAVE;
    const int vlo = su * G;                    // uniform slice bounds
    const int vhi = min(vlo + G, C);

    // append-only collect, branchless: always store, advance cursor on pass.
    // Failing keys either get overwritten or decode to >= ~R2LOOSE entries
    // that the exact end radius test rejects -> no correctness impact.
    int cnt = 0;
    auto EVAL = [&](const float4& c, int spos) {
        const float tt = fmaf(c.x, qx, fmaf(c.y, qy, fmaf(c.z, qz, c.w)));
        const float d2 = fmaxf(fmaf(-2.0f, tt, qs), 0.0f);
        const unsigned key =
            (__float_as_uint(d2) & KEYMASK) | (unsigned)spos;
        const int slot = cnt < (CAP - 1) ? cnt : (CAP - 1);
        sbuf[slot * NTHREADS + t] = key;
        cnt += (tt >= negthr) ? 1 : 0;
    };
    for (int r = 0; r < nr; ++r) {
        int a = vlo - cum[r]; if (a < 0) a = 0;
        int e = vhi - cum[r];
        const int len = phi[r] - plo[r];
        if (e > len) e = len;
        const int base = plo[r];           // uniform -> s_load fetches
        int j = a;
        for (; j + 4 <= e; j += 4) {
            const float4 c0 = csb[base + j];
            const float4 c1 = csb[base + j + 1];
            const float4 c2 = csb[base + j + 2];
            const float4 c3 = csb[base + j + 3];
            EVAL(c0, base + j);     EVAL(c1, base + j + 1);
            EVAL(c2, base + j + 2); EVAL(c3, base + j + 3);
        }
        for (; j < e; ++j) { const float4 c0 = csb[base + j]; EVAL(c0, base + j); }
    }

    // per-thread sort of collected keys into top-8
    unsigned md[KNN];
#pragma unroll
    for (int k = 0; k < KNN; ++k) md[k] = SENT;
    const int m = cnt < CAP ? cnt : CAP;
    for (int k = 0; k < m; ++k) {
        unsigned ky = sbuf[k * NTHREADS + t];
#pragma unroll
        for (int i = 0; i < KNN; ++i) {
            const unsigned mn = min(ky, md[i]);
            const unsigned mx = max(ky, md[i]);
            md[i] = mn; ky = mx;
        }
    }
    __syncthreads();   // collect reads done before row-relayout

    {   // publish sorted top-8 (row layout)
        uint4* bp = (uint4*)&sbuf[t * KNN];
        bp[0] = make_uint4(md[0], md[1], md[2], md[3]);
        bp[1] = make_uint4(md[4], md[5], md[6], md[7]);
    }
    __syncthreads();

    // wave 0: single-stage merge of the 8 partial lists per query,
    // exact radius test, emit orig-index fidx
    if (s == 0) {
        for (int l = 1; l < NWAVE; ++l) {
            const uint4* lp = (const uint4*)&sbuf[(l * QB + q) * KNN];
            const uint4 r0 = lp[0], r1 = lp[1];
            const unsigned tk[8] = {r0.x, r0.y, r0.z, r0.w,
                                    r1.x, r1.y, r1.z, r1.w};
#pragma unroll
            for (int k = 0; k < 8; ++k) {
                unsigned ky = tk[k];
                if (ky < md[KNN - 1]) {    // sentinel skip
#pragma unroll
                    for (int i = 0; i < KNN; ++i) {
                        const unsigned mn = min(ky, md[i]);
                        const unsigned mx = max(ky, md[i]);
                        md[i] = mn; ky = mx;
                    }
                }
            }
        }
#pragma unroll
        for (int k = 0; k < KNN; ++k) {
            const unsigned ky = md[k];
            int nb;
            if (ky >= SENT) {
                nb = qi;  // unfilled -> self (contributes 0, matches ref)
            } else {
                const int sp = (int)(ky & 0x1FFFu);
                const float4 cc = csb[sp];
                const float dx = cc.x - qx;
                const float dy = cc.y - qy;
                const float dz = cc.z - qz;
                const float d2 = fmaf(dx, dx, fmaf(dy, dy, dz * dz));
                // reference: idx = where(sqrt(d2) > 0.1, self_idx, idx)
                nb = (sqrtf(d2) > 0.1f) ? qi : sidx[b * NPTS + sp];
            }
            fidx[q * KNN + k] = nb;
        }
    }
    __syncthreads();

    // loss gather: 512 threads <-> 64 q x 8 nn, full 16-ch rows
    const int q2 = t >> 3;
    const int j2 = t & 7;
    const int qg = qid[q2];
    const int nb = fidx[q2 * KNN + j2];
    const float* mrow = mask + ((size_t)b * NPTS + qg) * KS;
    const float* nrow = mask + ((size_t)b * NPTS + nb) * KS;
    float acc = 0.0f;
#pragma unroll
    for (int c = 0; c < KS; c += 4) {
        const float4 a = *(const float4*)(mrow + c);
        const float4 v = *(const float4*)(nrow + c);
        acc += fabsf(a.x - v.x) + fabsf(a.y - v.y) +
               fabsf(a.z - v.z) + fabsf(a.w - v.w);
    }

    // block reduction: wave shuffle -> LDS -> one atomic per block
#pragma unroll
    for (int off = 32; off > 0; off >>= 1) acc += __shfl_down(acc, off);
    if ((t & 63) == 0) red[s] = acc;
    __syncthreads();
    if (t == 0) {
        float sum = 0.0f;
#pragma unroll
        for (int i = 0; i < NWAVE; ++i) sum += red[i];
        atomicAdd(out, sum * (1.0f / (BATCH * NPTS * KNN)));
    }
}

extern "C" void kernel_launch(void* const* d_in, const int* in_sizes, int n_in,
                              void* d_out, int out_size, void* d_ws, size_t ws_size,
                              hipStream_t stream) {
    const float* pc   = (const float*)d_in[0];  // (2, 8192, 3)
    const float* mask = (const float*)d_in[1];  // (2, 8192, 16)
    float* out = (float*)d_out;                 // scalar, poisoned 0xAA each call

    // workspace layout (344 KB used)
    float4* cs     = (float4*)d_ws;                              // 256 KB
    int*    sidx   = (int*)((char*)d_ws + 262144);               //  64 KB
    int*    cstart = (int*)((char*)d_ws + 327680);               //   8 KB
    int*    cfill  = (int*)((char*)d_ws + 335872);               //   8 KB

    hipMemsetAsync(cfill, 0, 2 * CSTRIDE * sizeof(int), stream);
    hipLaunchKernelGGL(count_kernel,   dim3(16), dim3(1024), 0, stream, pc, cfill);
    hipLaunchKernelGGL(scan_kernel,    dim3(2),  dim3(1024), 0, stream,
                       cfill, cstart, out);
    hipLaunchKernelGGL(scatter_kernel, dim3(16), dim3(1024), 0, stream,
                       pc, cs, sidx, cfill);
    hipLaunchKernelGGL(knn_loss_kernel, dim3(NBLK), dim3(512), 0, stream,
                       cs, sidx, cstart, mask, out);
}

// Round 8
// 87.575 us; speedup vs baseline: 5.1507x; 1.0187x over previous
//
#include <hip/hip_runtime.h>

// Problem constants (fixed by setup_inputs)
#define BATCH 2
#define NPTS  8192
#define KS    16
#define KNN   8
#define R2LOOSE 0.0101f      // loose prefilter ball; exact radius test at end
#define KEYMASK 0xFFFFE000u  // high 19 bits of d2; low 13 bits = sorted pos
#define NCELL   1000         // 10x10x10 grid, cell size 0.1 (= RADIUS)
#define CSTRIDE 1024         // padded per-batch cell-array stride

// Main kernel geometry
#define QB       64                 // queries per block (= wave size)
#define NWAVE    8                  // waves per block (512 threads)
#define NTHREADS 512
#define CAP      32                 // collect capacity per thread
#define NBLK     (BATCH * NPTS / QB)   // 256 blocks

__device__ __forceinline__ int cell_of(float x, float y, float z) {
    int cx = (int)(x * 10.0f); cx = cx > 9 ? 9 : cx;
    int cy = (int)(y * 10.0f); cy = cy > 9 ? 9 : cy;
    int cz = (int)(z * 10.0f); cz = cz > 9 ? 9 : cz;
    return (cx * 10 + cy) * 10 + cz;
}

// ---- grid build (parallel, small kernels) ----------------------------------
__global__ void count_kernel(const float* __restrict__ pc, int* cfill) {
    const int i = blockIdx.x * 1024 + threadIdx.x;   // 16 blocks -> 16384
    const float x = pc[3 * i], y = pc[3 * i + 1], z = pc[3 * i + 2];
    const int b = i >> 13;
    atomicAdd(&cfill[b * CSTRIDE + cell_of(x, y, z)], 1);
}

// exclusive prefix per batch; writes cstart, resets cfill to cursors,
// zeroes the output scalar (runs before main in-stream).
__global__ __launch_bounds__(1024) void scan_kernel(int* cfill, int* cstart,
                                                    float* out) {
    __shared__ int arr[1024];
    const int b = blockIdx.x, t = threadIdx.x;
    if (b == 0 && t == 0) out[0] = 0.0f;
    const int cnt = cfill[b * CSTRIDE + t];   // t >= NCELL slots are 0
    arr[t] = cnt;
    __syncthreads();
    for (int off = 1; off < 1024; off <<= 1) {
        const int v = (t >= off) ? arr[t - off] : 0;
        __syncthreads();
        arr[t] += v;
        __syncthreads();
    }
    const int excl = arr[t] - cnt;
    cstart[b * CSTRIDE + t] = excl;
    cfill[b * CSTRIDE + t]  = excl;
}

__global__ void scatter_kernel(const float* __restrict__ pc,
                               float4* __restrict__ cs,
                               int* __restrict__ sidx, int* cfill) {
    const int i = blockIdx.x * 1024 + threadIdx.x;   // 16 blocks -> 16384
    const float x = pc[3 * i], y = pc[3 * i + 1], z = pc[3 * i + 2];
    const int b = i >> 13;
    const float sq = fmaf(z, z, fmaf(y, y, x * x));
    const int pos = atomicAdd(&cfill[b * CSTRIDE + cell_of(x, y, z)], 1);
    cs[b * NPTS + pos]   = make_float4(x, y, z, -0.5f * sq);
    sidx[b * NPTS + pos] = i & (NPTS - 1);   // orig within-batch index
}

// ---- fused knn + loss ------------------------------------------------------
__global__ __launch_bounds__(512) void knn_loss_kernel(
    const float4* __restrict__ cs,     // cell-sorted (x,y,z,-0.5|c|^2)
    const int*    __restrict__ sidx,   // sorted pos -> orig idx
    const int*    __restrict__ cstart, // per-batch cell starts (padded 1024)
    const float*  __restrict__ mask,   // (B, N, KS) in ORIGINAL order
    float* __restrict__ out)
{
    // phase A (collect): column layout, word = slot*512 + tid (own column only)
    // phase B (merge):  row layout,    word = tid*8 + k
    __shared__ unsigned sbuf[CAP * NTHREADS];  // 64 KB
    __shared__ int      fidx[QB * KNN];        //  2 KB
    __shared__ int      qid[QB];
    __shared__ float    red[NWAVE];

    const int t = threadIdx.x;
    const int q = t & (QB - 1);   // query slot (lane)
    const int s = t >> 6;         // wave id 0..7
    const int su = __builtin_amdgcn_readfirstlane(s);  // wave-uniform wave id
    const int blk = blockIdx.x;
    const int b  = blk >> 7;
    const int q0 = (blk & 127) * QB;      // sorted-position base
    const int qpos = q0 + q;

    const float4* csb = cs + b * NPTS;
    const float4 qc = csb[qpos];
    const int    qi = sidx[b * NPTS + qpos];
    if (s == 0) qid[q] = qi;

    const float qx = qc.x, qy = qc.y, qz = qc.z;
    const float qs = -2.0f * qc.w;                 // exact (power of 2)
    const float negthr = (qs - R2LOOSE) * 0.5f;    // pass iff tt >= negthr
    const unsigned SENT = (__float_as_uint(R2LOOSE) & KEYMASK) | 0x1FFFu;

    // block's contiguous lex-cell run (all waves compute identically)
    int lex = cell_of(qx, qy, qz);
    int cmn = lex, cmx = lex;
#pragma unroll
    for (int off = 32; off; off >>= 1) {
        cmn = min(cmn, __shfl_xor(cmn, off));
        cmx = max(cmx, __shfl_xor(cmx, off));
    }
    const int cfirst = __builtin_amdgcn_readfirstlane(cmn);
    const int clast  = __builtin_amdgcn_readfirstlane(cmx);

    // Needed cells: lex + 100dx + 10dy + dz, |10dy+dz| <= 11. Three covering
    // intervals (one per dx cluster), NAMED SCALARS ONLY (no arrays -> no
    // scratch -> uniform s_load address chain). Clusters are >= 78-w apart;
    // the max() clamps enforce disjointness (dedup) in all cases. Spurious
    // wrapped cells are >= 0.8 away in the wrapped dim -> fail prefilter.
    int lo0 = cfirst - 111, h0 = clast - 89;
    int lo1 = cfirst - 11,  h1 = clast + 11;
    int lo2 = cfirst + 89,  h2 = clast + 111;
    lo0 = min(max(lo0, 0), 1000);
    lo1 = min(max(lo1, 0), 1000);
    lo2 = min(max(lo2, 0), 1000);
    int hp0 = min(max(h0 + 1, 0), 1000);
    int hp1 = min(max(h1 + 1, 0), 1000);
    int hp2 = min(max(h2 + 1, 0), 1000);
    lo1 = max(lo1, hp0);   // dedup guards (no-ops in the typical case)
    lo2 = max(lo2, hp1);

    const int* csp = cstart + b * CSTRIDE;
    const int P0 = csp[lo0], E0 = csp[hp0];
    const int P1 = csp[lo1], E1 = csp[hp1];
    const int P2 = csp[lo2], E2 = csp[hp2];
    const int L0 = max(0, E0 - P0);
    const int L1 = max(0, E1 - P1);
    const int L2 = max(0, E2 - P2);

    // append-only collect, branchless: always store, advance cursor on pass.
    // Overflow/garbage keys decode to >= ~R2LOOSE -> exact end test -> self.
    int cnt = 0;
    auto EVAL = [&](const float4& c, int spos) {
        const float tt = fmaf(c.x, qx, fmaf(c.y, qy, fmaf(c.z, qz, c.w)));
        const float d2 = fmaxf(fmaf(-2.0f, tt, qs), 0.0f);
        const unsigned key =
            (__float_as_uint(d2) & KEYMASK) | (unsigned)spos;
        const int slot = cnt < (CAP - 1) ? cnt : (CAP - 1);
        sbuf[slot * NTHREADS + t] = key;
        cnt += (tt >= negthr) ? 1 : 0;
    };
    auto SCAN = [&](int P, int L) {          // wave su's slice of [P, P+L)
        int j = (su * L) >> 3;
        const int e = ((su + 1) * L) >> 3;
        for (; j + 4 <= e; j += 4) {
            const float4 c0 = csb[P + j];
            const float4 c1 = csb[P + j + 1];
            const float4 c2 = csb[P + j + 2];
            const float4 c3 = csb[P + j + 3];
            EVAL(c0, P + j);     EVAL(c1, P + j + 1);
            EVAL(c2, P + j + 2); EVAL(c3, P + j + 3);
        }
        for (; j < e; ++j) { const float4 c0 = csb[P + j]; EVAL(c0, P + j); }
    };
    SCAN(P0, L0);
    SCAN(P1, L1);
    SCAN(P2, L2);

    // per-thread sort of collected keys into top-8
    unsigned md[KNN];
#pragma unroll
    for (int k = 0; k < KNN; ++k) md[k] = SENT;
    const int m = cnt < CAP ? cnt : CAP;
    for (int k = 0; k < m; ++k) {
        unsigned ky = sbuf[k * NTHREADS + t];
#pragma unroll
        for (int i = 0; i < KNN; ++i) {
            const unsigned mn = min(ky, md[i]);
            const unsigned mx = max(ky, md[i]);
            md[i] = mn; ky = mx;
        }
    }
    __syncthreads();   // collect reads done before row-relayout

    {   // publish sorted top-8 (row layout)
        uint4* bp = (uint4*)&sbuf[t * KNN];
        bp[0] = make_uint4(md[0], md[1], md[2], md[3]);
        bp[1] = make_uint4(md[4], md[5], md[6], md[7]);
    }
    __syncthreads();

    // wave 0: single-stage merge of the 8 partial lists per query,
    // exact radius test, emit orig-index fidx
    if (s == 0) {
        for (int l = 1; l < NWAVE; ++l) {
            const uint4* lp = (const uint4*)&sbuf[(l * QB + q) * KNN];
            const uint4 r0 = lp[0], r1 = lp[1];
            const unsigned tk[8] = {r0.x, r0.y, r0.z, r0.w,
                                    r1.x, r1.y, r1.z, r1.w};
#pragma unroll
            for (int k = 0; k < 8; ++k) {
                unsigned ky = tk[k];
                if (ky < md[KNN - 1]) {    // sentinel skip
#pragma unroll
                    for (int i = 0; i < KNN; ++i) {
                        const unsigned mn = min(ky, md[i]);
                        const unsigned mx = max(ky, md[i]);
                        md[i] = mn; ky = mx;
                    }
                }
            }
        }
#pragma unroll
        for (int k = 0; k < KNN; ++k) {
            const unsigned ky = md[k];
            int nb;
            if (ky >= SENT) {
                nb = qi;  // unfilled -> self (contributes 0, matches ref)
            } else {
                const int sp = (int)(ky & 0x1FFFu);
                const float4 cc = csb[sp];
                const float dx = cc.x - qx;
                const float dy = cc.y - qy;
                const float dz = cc.z - qz;
                const float d2 = fmaf(dx, dx, fmaf(dy, dy, dz * dz));
                // reference: idx = where(sqrt(d2) > 0.1, self_idx, idx)
                nb = (sqrtf(d2) > 0.1f) ? qi : sidx[b * NPTS + sp];
            }
            fidx[q * KNN + k] = nb;
        }
    }
    __syncthreads();

    // loss gather: 512 threads <-> 64 q x 8 nn, full 16-ch rows
    const int q2 = t >> 3;
    const int j2 = t & 7;
    const int qg = qid[q2];
    const int nb = fidx[q2 * KNN + j2];
    const float* mrow = mask + ((size_t)b * NPTS + qg) * KS;
    const float* nrow = mask + ((size_t)b * NPTS + nb) * KS;
    float acc = 0.0f;
#pragma unroll
    for (int c = 0; c < KS; c += 4) {
        const float4 a = *(const float4*)(mrow + c);
        const float4 v = *(const float4*)(nrow + c);
        acc += fabsf(a.x - v.x) + fabsf(a.y - v.y) +
               fabsf(a.z - v.z) + fabsf(a.w - v.w);
    }

    // block reduction: wave shuffle -> LDS -> one atomic per block
#pragma unroll
    for (int off = 32; off > 0; off >>= 1) acc += __shfl_down(acc, off);
    if ((t & 63) == 0) red[s] = acc;
    __syncthreads();
    if (t == 0) {
        float sum = 0.0f;
#pragma unroll
        for (int i = 0; i < NWAVE; ++i) sum += red[i];
        atomicAdd(out, sum * (1.0f / (BATCH * NPTS * KNN)));
    }
}

extern "C" void kernel_launch(void* const* d_in, const int* in_sizes, int n_in,
                              void* d_out, int out_size, void* d_ws, size_t ws_size,
                              hipStream_t stream) {
    const float* pc   = (const float*)d_in[0];  // (2, 8192, 3)
    const float* mask = (const float*)d_in[1];  // (2, 8192, 16)
    float* out = (float*)d_out;                 // scalar, poisoned 0xAA each call

    // workspace layout (344 KB used)
    float4* cs     = (float4*)d_ws;                              // 256 KB
    int*    sidx   = (int*)((char*)d_ws + 262144);               //  64 KB
    int*    cstart = (int*)((char*)d_ws + 327680);               //   8 KB
    int*    cfill  = (int*)((char*)d_ws + 335872);               //   8 KB

    hipMemsetAsync(cfill, 0, 2 * CSTRIDE * sizeof(int), stream);
    hipLaunchKernelGGL(count_kernel,   dim3(16), dim3(1024), 0, stream, pc, cfill);
    hipLaunchKernelGGL(scan_kernel,    dim3(2),  dim3(1024), 0, stream,
                       cfill, cstart, out);
    hipLaunchKernelGGL(scatter_kernel, dim3(16), dim3(1024), 0, stream,
                       pc, cs, sidx, cfill);
    hipLaunchKernelGGL(knn_loss_kernel, dim3(NBLK), dim3(512), 0, stream,
                       cs, sidx, cstart, mask, out);
}

// Round 9
// 84.029 us; speedup vs baseline: 5.3681x; 1.0422x over previous
//
#include <hip/hip_runtime.h>

// Problem constants (fixed by setup_inputs)
#define BATCH 2
#define NPTS  8192
#define KS    16
#define KNN   8
#define R2LOOSE 0.0101f      // loose prefilter ball; exact radius test at end
#define KEYMASK 0xFFFFE000u  // high 19 bits of d2; low 13 bits = sorted pos
#define NCELL   1000         // 10x10x10 grid, cell size 0.1 (= RADIUS)
#define CSTRIDE 1024         // padded per-batch cell-array stride

// Main kernel geometry
#define QB       64                 // queries per block (= wave size)
#define NWAVE    8                  // waves per block (512 threads)
#define NTHREADS 512
#define CAP      32                 // collect capacity per thread
#define TILEC    1024               // candidates staged per LDS tile
#define NBLK     (BATCH * NPTS / QB)   // 256 blocks

__device__ __forceinline__ int cell_of(float x, float y, float z) {
    int cx = (int)(x * 10.0f); cx = cx > 9 ? 9 : cx;
    int cy = (int)(y * 10.0f); cy = cy > 9 ? 9 : cy;
    int cz = (int)(z * 10.0f); cz = cz > 9 ? 9 : cz;
    return (cx * 10 + cy) * 10 + cz;
}

// ---- grid build (parallel, small kernels) ----------------------------------
__global__ void count_kernel(const float* __restrict__ pc, int* cfill) {
    const int i = blockIdx.x * 1024 + threadIdx.x;   // 16 blocks -> 16384
    const float x = pc[3 * i], y = pc[3 * i + 1], z = pc[3 * i + 2];
    const int b = i >> 13;
    atomicAdd(&cfill[b * CSTRIDE + cell_of(x, y, z)], 1);
}

// exclusive prefix per batch; writes cstart, resets cfill to cursors,
// zeroes the output scalar (runs before main in-stream).
__global__ __launch_bounds__(1024) void scan_kernel(int* cfill, int* cstart,
                                                    float* out) {
    __shared__ int arr[1024];
    const int b = blockIdx.x, t = threadIdx.x;
    if (b == 0 && t == 0) out[0] = 0.0f;
    const int cnt = cfill[b * CSTRIDE + t];   // t >= NCELL slots are 0
    arr[t] = cnt;
    __syncthreads();
    for (int off = 1; off < 1024; off <<= 1) {
        const int v = (t >= off) ? arr[t - off] : 0;
        __syncthreads();
        arr[t] += v;
        __syncthreads();
    }
    const int excl = arr[t] - cnt;
    cstart[b * CSTRIDE + t] = excl;
    cfill[b * CSTRIDE + t]  = excl;
}

__global__ void scatter_kernel(const float* __restrict__ pc,
                               float4* __restrict__ cs,
                               int* __restrict__ sidx, int* cfill) {
    const int i = blockIdx.x * 1024 + threadIdx.x;   // 16 blocks -> 16384
    const float x = pc[3 * i], y = pc[3 * i + 1], z = pc[3 * i + 2];
    const int b = i >> 13;
    const float sq = fmaf(z, z, fmaf(y, y, x * x));
    const int pos = atomicAdd(&cfill[b * CSTRIDE + cell_of(x, y, z)], 1);
    cs[b * NPTS + pos]   = make_float4(x, y, z, -0.5f * sq);
    sidx[b * NPTS + pos] = i & (NPTS - 1);   // orig within-batch index
}

// ---- fused knn + loss ------------------------------------------------------
__global__ __launch_bounds__(512) void knn_loss_kernel(
    const float4* __restrict__ cs,     // cell-sorted (x,y,z,-0.5|c|^2)
    const int*    __restrict__ sidx,   // sorted pos -> orig idx
    const int*    __restrict__ cstart, // per-batch cell starts (padded 1024)
    const float*  __restrict__ mask,   // (B, N, KS) in ORIGINAL order
    float* __restrict__ out)
{
    __shared__ float4   tile[TILEC];           // 16 KB staged candidates
    __shared__ int      tsp[TILEC];            //  4 KB their sorted positions
    // phase A (collect): column layout, word = slot*512 + tid (own column only)
    // phase B (merge):  row layout,    word = tid*8 + k
    __shared__ unsigned sbuf[CAP * NTHREADS];  // 64 KB
    __shared__ int      fidx[QB * KNN];        //  2 KB
    __shared__ int      qid[QB];
    __shared__ float    red[NWAVE];

    const int t = threadIdx.x;
    const int q = t & (QB - 1);   // query slot (lane)
    const int s = t >> 6;         // wave id 0..7
    const int su = __builtin_amdgcn_readfirstlane(s);  // wave-uniform wave id
    const int blk = blockIdx.x;
    const int b  = blk >> 7;
    const int q0 = (blk & 127) * QB;      // sorted-position base
    const int qpos = q0 + q;

    const float4* csb = cs + b * NPTS;
    const float4 qc = csb[qpos];
    const int    qi = sidx[b * NPTS + qpos];
    if (s == 0) qid[q] = qi;

    const float qx = qc.x, qy = qc.y, qz = qc.z;
    const float qs = -2.0f * qc.w;                 // exact (power of 2)
    const float negthr = (qs - R2LOOSE) * 0.5f;    // pass iff tt >= negthr
    const unsigned SENT = (__float_as_uint(R2LOOSE) & KEYMASK) | 0x1FFFu;

    // block's contiguous lex-cell run (all waves compute identically)
    int lex = cell_of(qx, qy, qz);
    int cmn = lex, cmx = lex;
#pragma unroll
    for (int off = 32; off; off >>= 1) {
        cmn = min(cmn, __shfl_xor(cmn, off));
        cmx = max(cmx, __shfl_xor(cmx, off));
    }
    const int cfirst = __builtin_amdgcn_readfirstlane(cmn);
    const int clast  = __builtin_amdgcn_readfirstlane(cmx);

    // Needed cells: lex + 100dx + 10dy + dz, |10dy+dz| <= 11. Three covering
    // intervals (one per dx cluster), named scalars only. Clamps enforce
    // disjointness; wrapped spurious cells fail the prefilter (>= 0.8 away).
    int lo0 = cfirst - 111, h0 = clast - 89;
    int lo1 = cfirst - 11,  h1 = clast + 11;
    int lo2 = cfirst + 89,  h2 = clast + 111;
    lo0 = min(max(lo0, 0), 1000);
    lo1 = min(max(lo1, 0), 1000);
    lo2 = min(max(lo2, 0), 1000);
    int hp0 = min(max(h0 + 1, 0), 1000);
    int hp1 = min(max(h1 + 1, 0), 1000);
    int hp2 = min(max(h2 + 1, 0), 1000);
    lo1 = max(lo1, hp0);   // dedup guards (no-ops in the typical case)
    lo2 = max(lo2, hp1);

    const int* csp = cstart + b * CSTRIDE;
    const int P0 = csp[lo0], E0 = csp[hp0];
    const int P1 = csp[lo1], E1 = csp[hp1];
    const int P2 = csp[lo2], E2 = csp[hp2];
    const int L0 = max(0, E0 - P0);
    const int L1 = max(0, E1 - P1);
    const int L2 = max(0, E2 - P2);
    const int C  = L0 + L1 + L2;        // total candidates (typ. ~760)

    // append-only collect, branchless: always store, advance cursor on pass.
    // Overflow/garbage keys decode to >= ~R2LOOSE -> exact end test -> self.
    int cnt = 0;
    auto EVAL = [&](const float4& c, int spos) {
        const float tt = fmaf(c.x, qx, fmaf(c.y, qy, fmaf(c.z, qz, c.w)));
        const float d2 = fmaxf(fmaf(-2.0f, tt, qs), 0.0f);
        const unsigned key =
            (__float_as_uint(d2) & KEYMASK) | (unsigned)spos;
        const int slot = cnt < (CAP - 1) ? cnt : (CAP - 1);
        sbuf[slot * NTHREADS + t] = key;
        cnt += (tt >= negthr) ? 1 : 0;
    };

    // Tiled collect: cooperative wide staging into LDS (full MLP, no load
    // chains), then wave-uniform broadcast scan from LDS.
    for (int tb = 0; tb < C; tb += TILEC) {
        const int nt = min(TILEC, C - tb);
        for (int p = t; p < nt; p += NTHREADS) {    // <= 2 iters, 512-wide
            const int g = tb + p;
            int sp = P0 + g;                         // flat -> sorted pos
            sp = (g >= L0)      ? (P1 + (g - L0))      : sp;
            sp = (g >= L0 + L1) ? (P2 + (g - L0 - L1)) : sp;
            tile[p] = csb[sp];                       // coalesced 16 B/lane
            tsp[p]  = sp;
        }
        __syncthreads();

        int j = (su * nt) >> 3;                      // wave's uniform slice
        const int e = ((su + 1) * nt) >> 3;
        for (; j + 4 <= e; j += 4) {
            const float4 c0 = tile[j],     c1 = tile[j + 1];
            const float4 c2 = tile[j + 2], c3 = tile[j + 3];
            const int s0 = tsp[j],     s1 = tsp[j + 1];
            const int s2 = tsp[j + 2], s3 = tsp[j + 3];
            EVAL(c0, s0); EVAL(c1, s1); EVAL(c2, s2); EVAL(c3, s3);
        }
        for (; j < e; ++j) { const float4 c0 = tile[j]; EVAL(c0, tsp[j]); }
        __syncthreads();
    }

    // per-thread sort of collected keys into top-8 (own column, no barrier)
    unsigned md[KNN];
#pragma unroll
    for (int k = 0; k < KNN; ++k) md[k] = SENT;
    const int m = cnt < CAP ? cnt : CAP;
    for (int k = 0; k < m; ++k) {
        unsigned ky = sbuf[k * NTHREADS + t];
#pragma unroll
        for (int i = 0; i < KNN; ++i) {
            const unsigned mn = min(ky, md[i]);
            const unsigned mx = max(ky, md[i]);
            md[i] = mn; ky = mx;
        }
    }
    __syncthreads();   // collect reads done before row-relayout

    {   // publish sorted top-8 (row layout)
        uint4* bp = (uint4*)&sbuf[t * KNN];
        bp[0] = make_uint4(md[0], md[1], md[2], md[3]);
        bp[1] = make_uint4(md[4], md[5], md[6], md[7]);
    }
    __syncthreads();

    // wave 0: single-stage merge of the 8 partial lists per query,
    // exact radius test, emit orig-index fidx
    if (s == 0) {
        for (int l = 1; l < NWAVE; ++l) {
            const uint4* lp = (const uint4*)&sbuf[(l * QB + q) * KNN];
            const uint4 r0 = lp[0], r1 = lp[1];
            const unsigned tk[8] = {r0.x, r0.y, r0.z, r0.w,
                                    r1.x, r1.y, r1.z, r1.w};
#pragma unroll
            for (int k = 0; k < 8; ++k) {
                unsigned ky = tk[k];
                if (ky < md[KNN - 1]) {    // sentinel skip
#pragma unroll
                    for (int i = 0; i < KNN; ++i) {
                        const unsigned mn = min(ky, md[i]);
                        const unsigned mx = max(ky, md[i]);
                        md[i] = mn; ky = mx;
                    }
                }
            }
        }
#pragma unroll
        for (int k = 0; k < KNN; ++k) {
            const unsigned ky = md[k];
            int nb;
            if (ky >= SENT) {
                nb = qi;  // unfilled -> self (contributes 0, matches ref)
            } else {
                const int sp = (int)(ky & 0x1FFFu);
                const float4 cc = csb[sp];
                const float dx = cc.x - qx;
                const float dy = cc.y - qy;
                const float dz = cc.z - qz;
                const float d2 = fmaf(dx, dx, fmaf(dy, dy, dz * dz));
                // reference: idx = where(sqrt(d2) > 0.1, self_idx, idx)
                nb = (sqrtf(d2) > 0.1f) ? qi : sidx[b * NPTS + sp];
            }
            fidx[q * KNN + k] = nb;
        }
    }
    __syncthreads();

    // loss gather: 512 threads <-> 64 q x 8 nn, full 16-ch rows
    const int q2 = t >> 3;
    const int j2 = t & 7;
    const int qg = qid[q2];
    const int nb = fidx[q2 * KNN + j2];
    const float* mrow = mask + ((size_t)b * NPTS + qg) * KS;
    const float* nrow = mask + ((size_t)b * NPTS + nb) * KS;
    float acc = 0.0f;
#pragma unroll
    for (int c = 0; c < KS; c += 4) {
        const float4 a = *(const float4*)(mrow + c);
        const float4 v = *(const float4*)(nrow + c);
        acc += fabsf(a.x - v.x) + fabsf(a.y - v.y) +
               fabsf(a.z - v.z) + fabsf(a.w - v.w);
    }

    // block reduction: wave shuffle -> LDS -> one atomic per block
#pragma unroll
    for (int off = 32; off > 0; off >>= 1) acc += __shfl_down(acc, off);
    if ((t & 63) == 0) red[s] = acc;
    __syncthreads();
    if (t == 0) {
        float sum = 0.0f;
#pragma unroll
        for (int i = 0; i < NWAVE; ++i) sum += red[i];
        atomicAdd(out, sum * (1.0f / (BATCH * NPTS * KNN)));
    }
}

extern "C" void kernel_launch(void* const* d_in, const int* in_sizes, int n_in,
                              void* d_out, int out_size, void* d_ws, size_t ws_size,
                              hipStream_t stream) {
    const float* pc   = (const float*)d_in[0];  // (2, 8192, 3)
    const float* mask = (const float*)d_in[1];  // (2, 8192, 16)
    float* out = (float*)d_out;                 // scalar, poisoned 0xAA each call

    // workspace layout (344 KB used)
    float4* cs     = (float4*)d_ws;                              // 256 KB
    int*    sidx   = (int*)((char*)d_ws + 262144);               //  64 KB
    int*    cstart = (int*)((char*)d_ws + 327680);               //   8 KB
    int*    cfill  = (int*)((char*)d_ws + 335872);               //   8 KB

    hipMemsetAsync(cfill, 0, 2 * CSTRIDE * sizeof(int), stream);
    hipLaunchKernelGGL(count_kernel,   dim3(16), dim3(1024), 0, stream, pc, cfill);
    hipLaunchKernelGGL(scan_kernel,    dim3(2),  dim3(1024), 0, stream,
                       cfill, cstart, out);
    hipLaunchKernelGGL(scatter_kernel, dim3(16), dim3(1024), 0, stream,
                       pc, cs, sidx, cfill);
    hipLaunchKernelGGL(knn_loss_kernel, dim3(NBLK), dim3(512), 0, stream,
                       cs, sidx, cstart, mask, out);
}